// Round 1
// baseline (607.129 us; speedup 1.0000x reference)
//
#include <hip/hip_runtime.h>
#include <hip/hip_bf16.h>
#include <math.h>

#define N_NODES 20000
#define N_EDGES 320000
#define IN_DIM 64
#define HID 128
#define HEADS 4
#define LAYERS 3
#define GRAPHS 64
#define TOT_E (N_EDGES + N_NODES)
#define NEG_SLOPE 0.2f
#define LN_EPS 1e-5f

// ---------------- CSR build (by dst), rebuilt deterministically every call ----------------

__global__ void count_kernel(const int* __restrict__ ei, int* __restrict__ counts) {
    int e = blockIdx.x * blockDim.x + threadIdx.x;
    if (e >= TOT_E) return;
    int dst = (e < N_EDGES) ? ei[N_EDGES + e] : (e - N_EDGES);
    atomicAdd(&counts[dst], 1);
}

__global__ void scan_kernel(const int* __restrict__ counts, int* __restrict__ row_ptr,
                            int* __restrict__ cursor) {
    __shared__ int part[1024];
    int tid = threadIdx.x;
    const int per = (N_NODES + 1023) / 1024;  // 20
    int start = tid * per;
    int end = start + per; if (end > N_NODES) end = N_NODES;
    int s = 0;
    for (int i = start; i < end; ++i) s += counts[i];
    part[tid] = s;
    __syncthreads();
    for (int off = 1; off < 1024; off <<= 1) {
        int v = (tid >= off) ? part[tid - off] : 0;
        __syncthreads();
        part[tid] += v;
        __syncthreads();
    }
    int run = (tid > 0) ? part[tid - 1] : 0;
    for (int i = start; i < end; ++i) {
        row_ptr[i] = run; cursor[i] = run; run += counts[i];
    }
    if (tid == 1023) row_ptr[N_NODES] = part[1023];
}

__global__ void fill_kernel(const int* __restrict__ ei, int* __restrict__ cursor,
                            int* __restrict__ colidx) {
    int e = blockIdx.x * blockDim.x + threadIdx.x;
    if (e >= TOT_E) return;
    int src, dst;
    if (e < N_EDGES) { src = ei[e]; dst = ei[N_EDGES + e]; }
    else { src = e - N_EDGES; dst = src; }
    int pos = atomicAdd(&cursor[dst], 1);
    colidx[pos] = src;
}

// ---------------- fp32 tiled GEMM: C[M][Nc] = A[M][K] @ B[K][Nc] (+bias) ----------------

#define BM 64
#define BN 64
#define BK 16

__global__ __launch_bounds__(256) void gemm_bias(
    const float* __restrict__ A, const float* __restrict__ B,
    const float* __restrict__ bias, float* __restrict__ C,
    int M, int K, int Nc) {
    __shared__ float As[BK][BM + 4];  // stride 68 floats = 272B (16B-aligned rows)
    __shared__ float Bs[BK][BN];
    int tid = threadIdx.x;
    int row0 = blockIdx.y * BM;
    int col0 = blockIdx.x * BN;
    int la_row = tid >> 2, la_k = (tid & 3) << 2;
    int lb_k = tid >> 4, lb_c = (tid & 15) << 2;
    int ty = tid >> 4, tx = tid & 15;
    float acc[4][4] = {};
    for (int kk = 0; kk < K; kk += BK) {
        int ar = row0 + la_row;
        float4 a4 = make_float4(0.f, 0.f, 0.f, 0.f);
        if (ar < M) a4 = *(const float4*)&A[(size_t)ar * K + kk + la_k];
        As[la_k + 0][la_row] = a4.x;
        As[la_k + 1][la_row] = a4.y;
        As[la_k + 2][la_row] = a4.z;
        As[la_k + 3][la_row] = a4.w;
        float4 b4 = *(const float4*)&B[(size_t)(kk + lb_k) * Nc + col0 + lb_c];
        *(float4*)&Bs[lb_k][lb_c] = b4;
        __syncthreads();
#pragma unroll
        for (int k = 0; k < BK; ++k) {
            float4 av = *(const float4*)&As[k][ty << 2];
            float4 bv = *(const float4*)&Bs[k][tx << 2];
            float a[4] = {av.x, av.y, av.z, av.w};
            float b[4] = {bv.x, bv.y, bv.z, bv.w};
#pragma unroll
            for (int i = 0; i < 4; ++i)
#pragma unroll
                for (int j = 0; j < 4; ++j)
                    acc[i][j] = fmaf(a[i], b[j], acc[i][j]);
        }
        __syncthreads();
    }
    int cbase = col0 + (tx << 2);
    float4 bv = make_float4(0.f, 0.f, 0.f, 0.f);
    if (bias) bv = *(const float4*)&bias[cbase];
#pragma unroll
    for (int i = 0; i < 4; ++i) {
        int r = row0 + (ty << 2) + i;
        if (r < M) {
            float4 o = make_float4(acc[i][0] + bv.x, acc[i][1] + bv.y,
                                   acc[i][2] + bv.z, acc[i][3] + bv.w);
            *(float4*)&C[(size_t)r * Nc + cbase] = o;
        }
    }
}

// ---------------- alpha_s / alpha_d: per-node per-head 128-dot ----------------

__global__ __launch_bounds__(128) void alpha_kernel(
    const float* __restrict__ hproj, const float* __restrict__ att_s,
    const float* __restrict__ att_d, float* __restrict__ a_s, float* __restrict__ a_d) {
    int n = blockIdx.x;
    int c = threadIdx.x;           // 0..127
    int lane = c & 63, wv = c >> 6;
    __shared__ float red[2][2][HEADS];
    const float* hp = &hproj[(size_t)n * (HEADS * HID)];
#pragma unroll
    for (int hh = 0; hh < HEADS; ++hh) {
        float v = hp[hh * HID + c];
        float ps = v * att_s[hh * HID + c];
        float pd = v * att_d[hh * HID + c];
#pragma unroll
        for (int off = 32; off; off >>= 1) {
            ps += __shfl_xor(ps, off);
            pd += __shfl_xor(pd, off);
        }
        if (lane == 0) { red[wv][0][hh] = ps; red[wv][1][hh] = pd; }
    }
    __syncthreads();
    if (c < HEADS) a_s[n * HEADS + c] = red[0][0][c] + red[1][0][c];
    else if (c >= 64 && c < 64 + HEADS) {
        int hh = c - 64;
        a_d[n * HEADS + hh] = red[0][1][hh] + red[1][1][hh];
    }
}

// ---- fused per-dst-node: segment softmax + weighted gather-sum + head-mean
// ---- + bias + relu + residual + LayerNorm. One wave per node, in-place h update.

__global__ __launch_bounds__(256) void edge_kernel(
    const int* __restrict__ row_ptr, const int* __restrict__ colidx,
    const float* __restrict__ hproj, const float* __restrict__ a_s,
    const float* __restrict__ a_d, const float* __restrict__ conv_b,
    const float* __restrict__ ln_g, const float* __restrict__ ln_b,
    float* __restrict__ h) {
    int wv = threadIdx.x >> 6;
    int lane = threadIdx.x & 63;
    int n = blockIdx.x * 4 + wv;
    if (n >= N_NODES) return;
    int beg = row_ptr[n], end = row_ptr[n + 1];
    float4 adv = *(const float4*)&a_d[n * 4];
    float ad[4] = {adv.x, adv.y, adv.z, adv.w};
    // pass 1: per-head max over incoming edges (lanes stride edges)
    float m[4] = {-3.4e38f, -3.4e38f, -3.4e38f, -3.4e38f};
    for (int i = beg + lane; i < end; i += 64) {
        int s = colidx[i];
        float4 asv = *(const float4*)&a_s[s * 4];
        float av[4] = {asv.x, asv.y, asv.z, asv.w};
#pragma unroll
        for (int hh = 0; hh < 4; ++hh) {
            float e = av[hh] + ad[hh];
            e = (e > 0.f) ? e : NEG_SLOPE * e;
            m[hh] = fmaxf(m[hh], e);
        }
    }
#pragma unroll
    for (int off = 32; off; off >>= 1)
#pragma unroll
        for (int hh = 0; hh < 4; ++hh)
            m[hh] = fmaxf(m[hh], __shfl_xor(m[hh], off));
    // pass 2: exp + denom + weighted accumulate (all lanes walk edges together,
    // each lane owns channels {2*lane, 2*lane+1} of all 4 heads)
    float denom[4] = {0.f, 0.f, 0.f, 0.f};
    float acc0[4] = {0.f, 0.f, 0.f, 0.f};
    float acc1[4] = {0.f, 0.f, 0.f, 0.f};
    for (int i = beg; i < end; ++i) {
        int s = colidx[i];
        float4 asv = *(const float4*)&a_s[s * 4];
        float av[4] = {asv.x, asv.y, asv.z, asv.w};
        float p[4];
#pragma unroll
        for (int hh = 0; hh < 4; ++hh) {
            float e = av[hh] + ad[hh];
            e = (e > 0.f) ? e : NEG_SLOPE * e;
            p[hh] = __expf(e - m[hh]);
            denom[hh] += p[hh];
        }
        const float2* hp = (const float2*)&hproj[(size_t)s * (HEADS * HID)];
#pragma unroll
        for (int hh = 0; hh < 4; ++hh) {
            float2 v = hp[hh * 64 + lane];
            acc0[hh] = fmaf(p[hh], v.x, acc0[hh]);
            acc1[hh] = fmaf(p[hh], v.y, acc1[hh]);
        }
    }
    float r0 = 0.f, r1 = 0.f;
#pragma unroll
    for (int hh = 0; hh < 4; ++hh) {
        float inv = 1.f / (denom[hh] + 1e-16f);
        r0 += acc0[hh] * inv;
        r1 += acc1[hh] * inv;
    }
    int c0 = lane * 2;
    r0 = 0.25f * r0 + conv_b[c0];
    r1 = 0.25f * r1 + conv_b[c0 + 1];
    r0 = fmaxf(r0, 0.f);
    r1 = fmaxf(r1, 0.f);
    float2 hold = *(const float2*)&h[(size_t)n * HID + c0];
    r0 += hold.x; r1 += hold.y;
    // LayerNorm over 128 channels (2 per lane)
    float s1 = r0 + r1;
#pragma unroll
    for (int off = 32; off; off >>= 1) s1 += __shfl_xor(s1, off);
    float mu = s1 * (1.f / HID);
    float d0 = r0 - mu, d1 = r1 - mu;
    float s2 = d0 * d0 + d1 * d1;
#pragma unroll
    for (int off = 32; off; off >>= 1) s2 += __shfl_xor(s2, off);
    float rstd = rsqrtf(s2 * (1.f / HID) + LN_EPS);
    float o0 = d0 * rstd * ln_g[c0] + ln_b[c0];
    float o1 = d1 * rstd * ln_g[c0 + 1] + ln_b[c0 + 1];
    *(float2*)&h[(size_t)n * HID + c0] = make_float2(o0, o1);
}

// ---------------- global mean pool (batch is sorted) ----------------

__global__ __launch_bounds__(128) void pool_kernel(
    const float* __restrict__ h, const int* __restrict__ batch,
    float* __restrict__ pool_sum, int* __restrict__ pool_cnt) {
    int base = blockIdx.x * 64;
    int c = threadIdx.x;
    float acc = 0.f; int cur = -1;
    for (int i = 0; i < 64; ++i) {
        int n = base + i;
        if (n >= N_NODES) break;
        int g = batch[n];
        if (g != cur) {
            if (cur >= 0) atomicAdd(&pool_sum[cur * HID + c], acc);
            acc = 0.f; cur = g;
        }
        acc += h[(size_t)n * HID + c];
    }
    if (cur >= 0) atomicAdd(&pool_sum[cur * HID + c], acc);
    if (c == 0) {
        int run = 0; int curg = -1;
        for (int i = 0; i < 64; ++i) {
            int n = base + i;
            if (n >= N_NODES) break;
            int g = batch[n];
            if (g != curg) {
                if (curg >= 0) atomicAdd(&pool_cnt[curg], run);
                curg = g; run = 0;
            }
            run++;
        }
        if (curg >= 0) atomicAdd(&pool_cnt[curg], run);
    }
}

__global__ void finalize_kernel(const float* __restrict__ pool_sum,
                                const int* __restrict__ pool_cnt,
                                float* __restrict__ out) {
    int i = blockIdx.x * blockDim.x + threadIdx.x;
    if (i >= GRAPHS * HID) return;
    int g = i / HID;
    int c = pool_cnt[g];
    float cnt = (float)(c > 0 ? c : 1);
    out[i] = pool_sum[i] / cnt;
}

// ---------------- host ----------------

extern "C" void kernel_launch(void* const* d_in, const int* in_sizes, int n_in,
                              void* d_out, int out_size, void* d_ws, size_t ws_size,
                              hipStream_t stream) {
    const float* x      = (const float*)d_in[0];
    const int*   ei     = (const int*)d_in[1];
    const int*   batch  = (const int*)d_in[2];
    const float* W_in   = (const float*)d_in[3];
    const float* b_in   = (const float*)d_in[4];
    const float* Ws     = (const float*)d_in[5];
    const float* att_src= (const float*)d_in[6];
    const float* att_dst= (const float*)d_in[7];
    const float* conv_b = (const float*)d_in[8];
    const float* ln_g   = (const float*)d_in[9];
    const float* ln_b   = (const float*)d_in[10];
    float* out = (float*)d_out;

    char* ws = (char*)d_ws;
    size_t off = 0;
    auto alloc = [&](size_t bytes) -> void* {
        void* p = ws + off;
        off = (off + bytes + 255) & ~(size_t)255;
        return p;
    };
    float* h      = (float*)alloc((size_t)N_NODES * HID * 4);
    float* hproj  = (float*)alloc((size_t)N_NODES * HEADS * HID * 4);
    float* a_s    = (float*)alloc((size_t)N_NODES * HEADS * 4);
    float* a_d    = (float*)alloc((size_t)N_NODES * HEADS * 4);
    int* row_ptr  = (int*)alloc((N_NODES + 1) * 4);
    int* cursor   = (int*)alloc(N_NODES * 4);
    int* colidx   = (int*)alloc((size_t)TOT_E * 4);
    int* counts   = (int*)alloc(N_NODES * 4);
    float* pool   = (float*)alloc(GRAPHS * HID * 4);
    int* cnt      = (int*)alloc(GRAPHS * 4);

    hipMemsetAsync(counts, 0, N_NODES * 4, stream);
    hipMemsetAsync(pool, 0, GRAPHS * HID * 4, stream);
    hipMemsetAsync(cnt, 0, GRAPHS * 4, stream);

    count_kernel<<<(TOT_E + 255) / 256, 256, 0, stream>>>(ei, counts);
    scan_kernel<<<1, 1024, 0, stream>>>(counts, row_ptr, cursor);
    fill_kernel<<<(TOT_E + 255) / 256, 256, 0, stream>>>(ei, cursor, colidx);

    dim3 g_in(HID / BN, (N_NODES + BM - 1) / BM);
    gemm_bias<<<g_in, 256, 0, stream>>>(x, W_in, b_in, h, N_NODES, IN_DIM, HID);

    for (int l = 0; l < LAYERS; ++l) {
        dim3 g_p((HEADS * HID) / BN, (N_NODES + BM - 1) / BM);
        gemm_bias<<<g_p, 256, 0, stream>>>(h, Ws + (size_t)l * HID * HEADS * HID,
                                           nullptr, hproj, N_NODES, HID, HEADS * HID);
        alpha_kernel<<<N_NODES, 128, 0, stream>>>(
            hproj, att_src + (size_t)l * HEADS * HID, att_dst + (size_t)l * HEADS * HID,
            a_s, a_d);
        edge_kernel<<<(N_NODES + 3) / 4, 256, 0, stream>>>(
            row_ptr, colidx, hproj, a_s, a_d,
            conv_b + (size_t)l * HID, ln_g + (size_t)l * HID, ln_b + (size_t)l * HID, h);
    }

    pool_kernel<<<(N_NODES + 63) / 64, 128, 0, stream>>>(h, batch, pool, cnt);
    finalize_kernel<<<(GRAPHS * HID + 255) / 256, 256, 0, stream>>>(pool, cnt, out);
}

// Round 2
// 386.484 us; speedup vs baseline: 1.5709x; 1.5709x over previous
//
#include <hip/hip_runtime.h>
#include <hip/hip_bf16.h>
#include <math.h>

#define N_NODES 20000
#define N_EDGES 320000
#define IN_DIM 64
#define HID 128
#define HEADS 4
#define LAYERS 3
#define GRAPHS 64
#define TOT_E (N_EDGES + N_NODES)
#define NEG_SLOPE 0.2f
#define LN_EPS 1e-5f

typedef __attribute__((ext_vector_type(8))) short short8v;
typedef __attribute__((ext_vector_type(4))) float f32x4;

// ---------------- CSR build (by dst), rebuilt deterministically every call ----------------

__global__ void count_kernel(const int* __restrict__ ei, int* __restrict__ counts) {
    int e = blockIdx.x * blockDim.x + threadIdx.x;
    if (e >= TOT_E) return;
    int dst = (e < N_EDGES) ? ei[N_EDGES + e] : (e - N_EDGES);
    atomicAdd(&counts[dst], 1);
}

__global__ void scan_kernel(const int* __restrict__ counts, int* __restrict__ row_ptr,
                            int* __restrict__ cursor) {
    __shared__ int part[1024];
    int tid = threadIdx.x;
    const int per = (N_NODES + 1023) / 1024;  // 20
    int start = tid * per;
    int end = start + per; if (end > N_NODES) end = N_NODES;
    int s = 0;
    for (int i = start; i < end; ++i) s += counts[i];
    part[tid] = s;
    __syncthreads();
    for (int off = 1; off < 1024; off <<= 1) {
        int v = (tid >= off) ? part[tid - off] : 0;
        __syncthreads();
        part[tid] += v;
        __syncthreads();
    }
    int run = (tid > 0) ? part[tid - 1] : 0;
    for (int i = start; i < end; ++i) {
        row_ptr[i] = run; cursor[i] = run; run += counts[i];
    }
    if (tid == 1023) row_ptr[N_NODES] = part[1023];
}

__global__ void fill_kernel(const int* __restrict__ ei, int* __restrict__ cursor,
                            int* __restrict__ colidx) {
    int e = blockIdx.x * blockDim.x + threadIdx.x;
    if (e >= TOT_E) return;
    int src, dst;
    if (e < N_EDGES) { src = ei[e]; dst = ei[N_EDGES + e]; }
    else { src = e - N_EDGES; dst = src; }
    int pos = atomicAdd(&cursor[dst], 1);
    colidx[pos] = src;
}

// ---------------- weights: transpose-cast Ws[l][k][n] -> Wt[l][n][k] bf16 ----------------

__global__ void pack_w(const float* __restrict__ Ws, __hip_bfloat16* __restrict__ Wt) {
    int i = blockIdx.x * blockDim.x + threadIdx.x;
    if (i >= LAYERS * 512 * 128) return;
    int l = i / (512 * 128);
    int r = i % (512 * 128);
    int n = r / 128, k = r % 128;
    Wt[i] = __float2bfloat16(Ws[(size_t)l * 128 * 512 + k * 512 + n]);
}

// ---------------- fp32 tiled GEMM (input layer only): writes fp32 + bf16 ----------------

#define BM 64
#define BN 64
#define BK 16

__global__ __launch_bounds__(256) void gemm_bias(
    const float* __restrict__ A, const float* __restrict__ B,
    const float* __restrict__ bias, float* __restrict__ C,
    __hip_bfloat16* __restrict__ Cb, int M, int K, int Nc) {
    __shared__ float As[BK][BM + 4];
    __shared__ float Bs[BK][BN];
    int tid = threadIdx.x;
    int row0 = blockIdx.y * BM;
    int col0 = blockIdx.x * BN;
    int la_row = tid >> 2, la_k = (tid & 3) << 2;
    int lb_k = tid >> 4, lb_c = (tid & 15) << 2;
    int ty = tid >> 4, tx = tid & 15;
    float acc[4][4] = {};
    for (int kk = 0; kk < K; kk += BK) {
        int ar = row0 + la_row;
        float4 a4 = make_float4(0.f, 0.f, 0.f, 0.f);
        if (ar < M) a4 = *(const float4*)&A[(size_t)ar * K + kk + la_k];
        As[la_k + 0][la_row] = a4.x;
        As[la_k + 1][la_row] = a4.y;
        As[la_k + 2][la_row] = a4.z;
        As[la_k + 3][la_row] = a4.w;
        float4 b4 = *(const float4*)&B[(size_t)(kk + lb_k) * Nc + col0 + lb_c];
        *(float4*)&Bs[lb_k][lb_c] = b4;
        __syncthreads();
#pragma unroll
        for (int k = 0; k < BK; ++k) {
            float4 av = *(const float4*)&As[k][ty << 2];
            float4 bv = *(const float4*)&Bs[k][tx << 2];
            float a[4] = {av.x, av.y, av.z, av.w};
            float b[4] = {bv.x, bv.y, bv.z, bv.w};
#pragma unroll
            for (int i = 0; i < 4; ++i)
#pragma unroll
                for (int j = 0; j < 4; ++j)
                    acc[i][j] = fmaf(a[i], b[j], acc[i][j]);
        }
        __syncthreads();
    }
    int cbase = col0 + (tx << 2);
    float4 bv = make_float4(0.f, 0.f, 0.f, 0.f);
    if (bias) bv = *(const float4*)&bias[cbase];
#pragma unroll
    for (int i = 0; i < 4; ++i) {
        int r = row0 + (ty << 2) + i;
        if (r < M) {
            float4 o = make_float4(acc[i][0] + bv.x, acc[i][1] + bv.y,
                                   acc[i][2] + bv.z, acc[i][3] + bv.w);
            *(float4*)&C[(size_t)r * Nc + cbase] = o;
            if (Cb) {
                __hip_bfloat162 p0, p1;
                p0.x = __float2bfloat16(o.x); p0.y = __float2bfloat16(o.y);
                p1.x = __float2bfloat16(o.z); p1.y = __float2bfloat16(o.w);
                *(__hip_bfloat162*)&Cb[(size_t)r * Nc + cbase] = p0;
                *(__hip_bfloat162*)&Cb[(size_t)r * Nc + cbase + 2] = p1;
            }
        }
    }
}

// ---------------- bf16 MFMA GEMM: hproj[M][512] = h_bf16[M][128] @ W^T, fused alphas ----
// Block: 256 thr = 4 waves (2M x 2N), tile 128x128. blockIdx.x = head (col block of 128).
// No LDS staging: A fragments direct from row-major h_bf16, B from Wt[n][k].

__global__ __launch_bounds__(256) void gemm_mfma(
    const __hip_bfloat16* __restrict__ A,   // [M][128]
    const __hip_bfloat16* __restrict__ Bt,  // [512][128]
    const float* __restrict__ att_s_l,      // [HEADS][128]
    const float* __restrict__ att_d_l,
    __hip_bfloat16* __restrict__ C,         // [M][512]
    float* __restrict__ a_s, float* __restrict__ a_d) {
    const int M_ = N_NODES;
    int tid = threadIdx.x;
    int lane = tid & 63, w = tid >> 6;
    int wm = w >> 1, wn = w & 1;
    int head = blockIdx.x;
    int row0 = blockIdx.y * 128 + wm * 64;
    int col0 = head * 128 + wn * 64;
    int lr = lane & 15, lg = lane >> 4;

    f32x4 acc[4][4] = {};
#pragma unroll
    for (int ks = 0; ks < 4; ++ks) {
        int kbase = ks * 32 + lg * 8;
        short8v a[4], b[4];
#pragma unroll
        for (int mf = 0; mf < 4; ++mf) {
            int r = row0 + mf * 16 + lr;
            if (r >= M_) r = M_ - 1;
            a[mf] = *(const short8v*)&A[(size_t)r * 128 + kbase];
        }
#pragma unroll
        for (int nf = 0; nf < 4; ++nf) {
            int c = col0 + nf * 16 + lr;
            b[nf] = *(const short8v*)&Bt[(size_t)c * 128 + kbase];
        }
#pragma unroll
        for (int mf = 0; mf < 4; ++mf)
#pragma unroll
            for (int nf = 0; nf < 4; ++nf)
                acc[mf][nf] = __builtin_amdgcn_mfma_f32_16x16x32_bf16(
                    a[mf], b[nf], acc[mf][nf], 0, 0, 0);
    }

    // store hproj bf16
#pragma unroll
    for (int mf = 0; mf < 4; ++mf) {
#pragma unroll
        for (int nf = 0; nf < 4; ++nf) {
#pragma unroll
            for (int j = 0; j < 4; ++j) {
                int r = row0 + mf * 16 + lg * 4 + j;
                int c = col0 + nf * 16 + lr;
                if (r < M_) C[(size_t)r * 512 + c] = __float2bfloat16(acc[mf][nf][j]);
            }
        }
    }

    // fused alpha: per lane, dot of its 4 cols with att vectors, reduce over lr
    float asv[4], adv_[4];
#pragma unroll
    for (int nf = 0; nf < 4; ++nf) {
        int cc = wn * 64 + nf * 16 + lr;      // channel within head
        asv[nf] = att_s_l[head * HID + cc];
        adv_[nf] = att_d_l[head * HID + cc];
    }
    __shared__ float sRed[2][2][2][64];       // [wm][wn][s/d][row-in-wave]
#pragma unroll
    for (int mf = 0; mf < 4; ++mf) {
#pragma unroll
        for (int j = 0; j < 4; ++j) {
            float ps = 0.f, pd = 0.f;
#pragma unroll
            for (int nf = 0; nf < 4; ++nf) {
                ps = fmaf(acc[mf][nf][j], asv[nf], ps);
                pd = fmaf(acc[mf][nf][j], adv_[nf], pd);
            }
#pragma unroll
            for (int off = 1; off < 16; off <<= 1) {
                ps += __shfl_xor(ps, off);
                pd += __shfl_xor(pd, off);
            }
            if (lr == 0) {
                sRed[wm][wn][0][mf * 16 + lg * 4 + j] = ps;
                sRed[wm][wn][1][mf * 16 + lg * 4 + j] = pd;
            }
        }
    }
    __syncthreads();
    {
        int sd = tid >> 7;        // 0..1
        int rr = tid & 127;       // row within block tile
        int wm_ = rr >> 6, rin = rr & 63;
        float v = sRed[wm_][0][sd][rin] + sRed[wm_][1][sd][rin];
        int gr = blockIdx.y * 128 + rr;
        if (gr < M_) (sd ? a_d : a_s)[gr * HEADS + head] = v;
    }
}

// ---- fused per-dst-node: segment softmax + weighted bf16 gather-sum + head-mean
// ---- + bias + relu + residual + LayerNorm. One wave per node, writes h fp32 + bf16.

__global__ __launch_bounds__(256) void edge_kernel(
    const int* __restrict__ row_ptr, const int* __restrict__ colidx,
    const __hip_bfloat16* __restrict__ hproj, const float* __restrict__ a_s,
    const float* __restrict__ a_d, const float* __restrict__ conv_b,
    const float* __restrict__ ln_g, const float* __restrict__ ln_b,
    float* __restrict__ h, __hip_bfloat16* __restrict__ hb) {
    int wv = threadIdx.x >> 6;
    int lane = threadIdx.x & 63;
    int n = blockIdx.x * 4 + wv;
    if (n >= N_NODES) return;
    int beg = row_ptr[n], end = row_ptr[n + 1];
    float4 adv = *(const float4*)&a_d[n * 4];
    float ad[4] = {adv.x, adv.y, adv.z, adv.w};
    // pass 1: per-head max over incoming edges (lanes stride edges)
    float m[4] = {-3.4e38f, -3.4e38f, -3.4e38f, -3.4e38f};
    for (int i = beg + lane; i < end; i += 64) {
        int s = colidx[i];
        float4 asv = *(const float4*)&a_s[s * 4];
        float av[4] = {asv.x, asv.y, asv.z, asv.w};
#pragma unroll
        for (int hh = 0; hh < 4; ++hh) {
            float e = av[hh] + ad[hh];
            e = (e > 0.f) ? e : NEG_SLOPE * e;
            m[hh] = fmaxf(m[hh], e);
        }
    }
#pragma unroll
    for (int off = 32; off; off >>= 1)
#pragma unroll
        for (int hh = 0; hh < 4; ++hh)
            m[hh] = fmaxf(m[hh], __shfl_xor(m[hh], off));
    // pass 2: exp + denom + weighted accumulate; lane owns channels {2*lane, 2*lane+1}
    float denom[4] = {0.f, 0.f, 0.f, 0.f};
    float acc0[4] = {0.f, 0.f, 0.f, 0.f};
    float acc1[4] = {0.f, 0.f, 0.f, 0.f};
    for (int i = beg; i < end; ++i) {
        int s = colidx[i];
        float4 asv = *(const float4*)&a_s[s * 4];
        float av[4] = {asv.x, asv.y, asv.z, asv.w};
        float p[4];
#pragma unroll
        for (int hh = 0; hh < 4; ++hh) {
            float e = av[hh] + ad[hh];
            e = (e > 0.f) ? e : NEG_SLOPE * e;
            p[hh] = __expf(e - m[hh]);
            denom[hh] += p[hh];
        }
        const unsigned int* hp = (const unsigned int*)(hproj + (size_t)s * (HEADS * HID));
#pragma unroll
        for (int hh = 0; hh < 4; ++hh) {
            unsigned int u = hp[hh * 64 + lane];
            float vx = __uint_as_float(u << 16);
            float vy = __uint_as_float(u & 0xffff0000u);
            acc0[hh] = fmaf(p[hh], vx, acc0[hh]);
            acc1[hh] = fmaf(p[hh], vy, acc1[hh]);
        }
    }
    float r0 = 0.f, r1 = 0.f;
#pragma unroll
    for (int hh = 0; hh < 4; ++hh) {
        float inv = 1.f / (denom[hh] + 1e-16f);
        r0 += acc0[hh] * inv;
        r1 += acc1[hh] * inv;
    }
    int c0 = lane * 2;
    r0 = 0.25f * r0 + conv_b[c0];
    r1 = 0.25f * r1 + conv_b[c0 + 1];
    r0 = fmaxf(r0, 0.f);
    r1 = fmaxf(r1, 0.f);
    float2 hold = *(const float2*)&h[(size_t)n * HID + c0];
    r0 += hold.x; r1 += hold.y;
    // LayerNorm over 128 channels (2 per lane)
    float s1 = r0 + r1;
#pragma unroll
    for (int off = 32; off; off >>= 1) s1 += __shfl_xor(s1, off);
    float mu = s1 * (1.f / HID);
    float d0 = r0 - mu, d1 = r1 - mu;
    float s2 = d0 * d0 + d1 * d1;
#pragma unroll
    for (int off = 32; off; off >>= 1) s2 += __shfl_xor(s2, off);
    float rstd = rsqrtf(s2 * (1.f / HID) + LN_EPS);
    float o0 = d0 * rstd * ln_g[c0] + ln_b[c0];
    float o1 = d1 * rstd * ln_g[c0 + 1] + ln_b[c0 + 1];
    *(float2*)&h[(size_t)n * HID + c0] = make_float2(o0, o1);
    __hip_bfloat162 hv;
    hv.x = __float2bfloat16(o0); hv.y = __float2bfloat16(o1);
    *(__hip_bfloat162*)&hb[(size_t)n * HID + c0] = hv;
}

// ---------------- global mean pool (batch is sorted) ----------------

__global__ __launch_bounds__(128) void pool_kernel(
    const float* __restrict__ h, const int* __restrict__ batch,
    float* __restrict__ pool_sum, int* __restrict__ pool_cnt) {
    int base = blockIdx.x * 64;
    int c = threadIdx.x;
    float acc = 0.f; int cur = -1;
    for (int i = 0; i < 64; ++i) {
        int n = base + i;
        if (n >= N_NODES) break;
        int g = batch[n];
        if (g != cur) {
            if (cur >= 0) atomicAdd(&pool_sum[cur * HID + c], acc);
            acc = 0.f; cur = g;
        }
        acc += h[(size_t)n * HID + c];
    }
    if (cur >= 0) atomicAdd(&pool_sum[cur * HID + c], acc);
    if (c == 0) {
        int run = 0; int curg = -1;
        for (int i = 0; i < 64; ++i) {
            int n = base + i;
            if (n >= N_NODES) break;
            int g = batch[n];
            if (g != curg) {
                if (curg >= 0) atomicAdd(&pool_cnt[curg], run);
                curg = g; run = 0;
            }
            run++;
        }
        if (curg >= 0) atomicAdd(&pool_cnt[curg], run);
    }
}

__global__ void finalize_kernel(const float* __restrict__ pool_sum,
                                const int* __restrict__ pool_cnt,
                                float* __restrict__ out) {
    int i = blockIdx.x * blockDim.x + threadIdx.x;
    if (i >= GRAPHS * HID) return;
    int g = i / HID;
    int c = pool_cnt[g];
    float cnt = (float)(c > 0 ? c : 1);
    out[i] = pool_sum[i] / cnt;
}

// ---------------- host ----------------

extern "C" void kernel_launch(void* const* d_in, const int* in_sizes, int n_in,
                              void* d_out, int out_size, void* d_ws, size_t ws_size,
                              hipStream_t stream) {
    const float* x      = (const float*)d_in[0];
    const int*   ei     = (const int*)d_in[1];
    const int*   batch  = (const int*)d_in[2];
    const float* W_in   = (const float*)d_in[3];
    const float* b_in   = (const float*)d_in[4];
    const float* Ws     = (const float*)d_in[5];
    const float* att_src= (const float*)d_in[6];
    const float* att_dst= (const float*)d_in[7];
    const float* conv_b = (const float*)d_in[8];
    const float* ln_g   = (const float*)d_in[9];
    const float* ln_b   = (const float*)d_in[10];
    float* out = (float*)d_out;

    char* ws = (char*)d_ws;
    size_t off = 0;
    auto alloc = [&](size_t bytes) -> void* {
        void* p = ws + off;
        off = (off + bytes + 255) & ~(size_t)255;
        return p;
    };
    float* h            = (float*)alloc((size_t)N_NODES * HID * 4);
    __hip_bfloat16* hb  = (__hip_bfloat16*)alloc((size_t)N_NODES * HID * 2);
    __hip_bfloat16* hpj = (__hip_bfloat16*)alloc((size_t)N_NODES * HEADS * HID * 2);
    __hip_bfloat16* Wt  = (__hip_bfloat16*)alloc((size_t)LAYERS * 512 * 128 * 2);
    float* a_s    = (float*)alloc((size_t)N_NODES * HEADS * 4);
    float* a_d    = (float*)alloc((size_t)N_NODES * HEADS * 4);
    int* row_ptr  = (int*)alloc((N_NODES + 1) * 4);
    int* cursor   = (int*)alloc(N_NODES * 4);
    int* colidx   = (int*)alloc((size_t)TOT_E * 4);
    int* counts   = (int*)alloc(N_NODES * 4);
    float* pool   = (float*)alloc(GRAPHS * HID * 4);
    int* cnt      = (int*)alloc(GRAPHS * 4);

    hipMemsetAsync(counts, 0, N_NODES * 4, stream);
    hipMemsetAsync(pool, 0, GRAPHS * HID * 4, stream);
    hipMemsetAsync(cnt, 0, GRAPHS * 4, stream);

    count_kernel<<<(TOT_E + 255) / 256, 256, 0, stream>>>(ei, counts);
    scan_kernel<<<1, 1024, 0, stream>>>(counts, row_ptr, cursor);
    fill_kernel<<<(TOT_E + 255) / 256, 256, 0, stream>>>(ei, cursor, colidx);
    pack_w<<<(LAYERS * 512 * 128 + 255) / 256, 256, 0, stream>>>(Ws, Wt);

    dim3 g_in(HID / BN, (N_NODES + BM - 1) / BM);
    gemm_bias<<<g_in, 256, 0, stream>>>(x, W_in, b_in, h, hb, N_NODES, IN_DIM, HID);

    for (int l = 0; l < LAYERS; ++l) {
        dim3 g_p(HEADS, (N_NODES + 127) / 128);
        gemm_mfma<<<g_p, 256, 0, stream>>>(
            hb, Wt + (size_t)l * 512 * 128,
            att_src + (size_t)l * HEADS * HID, att_dst + (size_t)l * HEADS * HID,
            hpj, a_s, a_d);
        edge_kernel<<<(N_NODES + 3) / 4, 256, 0, stream>>>(
            row_ptr, colidx, hpj, a_s, a_d,
            conv_b + (size_t)l * HID, ln_g + (size_t)l * HID, ln_b + (size_t)l * HID,
            h, hb);
    }

    pool_kernel<<<(N_NODES + 63) / 64, 128, 0, stream>>>(h, batch, pool, cnt);
    finalize_kernel<<<(GRAPHS * HID + 255) / 256, 256, 0, stream>>>(pool, cnt, out);
}

// Round 3
// 338.762 us; speedup vs baseline: 1.7922x; 1.1409x over previous
//
#include <hip/hip_runtime.h>
#include <hip/hip_bf16.h>
#include <math.h>

#define N_NODES 20000
#define N_EDGES 320000
#define IN_DIM 64
#define HID 128
#define HEADS 4
#define LAYERS 3
#define GRAPHS 64
#define TOT_E (N_EDGES + N_NODES)
#define NEG_SLOPE 0.2f
#define LN_EPS 1e-5f
#define MAXD 96   // fast-path max degree (Poisson(17): P(>96) ~ 1e-40); fallback below

typedef __attribute__((ext_vector_type(8))) short short8v;
typedef __attribute__((ext_vector_type(4))) float f32x4;

// ---------------- CSR build (by dst), rebuilt deterministically every call ----------------

__global__ void count_kernel(const int* __restrict__ ei, int* __restrict__ counts) {
    int e = blockIdx.x * blockDim.x + threadIdx.x;
    if (e >= TOT_E) return;
    int dst = (e < N_EDGES) ? ei[N_EDGES + e] : (e - N_EDGES);
    atomicAdd(&counts[dst], 1);
}

__global__ void scan_kernel(const int* __restrict__ counts, int* __restrict__ row_ptr,
                            int* __restrict__ cursor) {
    __shared__ int part[1024];
    int tid = threadIdx.x;
    const int per = (N_NODES + 1023) / 1024;  // 20
    int start = tid * per;
    int end = start + per; if (end > N_NODES) end = N_NODES;
    int s = 0;
    for (int i = start; i < end; ++i) s += counts[i];
    part[tid] = s;
    __syncthreads();
    for (int off = 1; off < 1024; off <<= 1) {
        int v = (tid >= off) ? part[tid - off] : 0;
        __syncthreads();
        part[tid] += v;
        __syncthreads();
    }
    int run = (tid > 0) ? part[tid - 1] : 0;
    for (int i = start; i < end; ++i) {
        row_ptr[i] = run; cursor[i] = run; run += counts[i];
    }
    if (tid == 1023) row_ptr[N_NODES] = part[1023];
}

__global__ void fill_kernel(const int* __restrict__ ei, int* __restrict__ cursor,
                            int* __restrict__ colidx) {
    int e = blockIdx.x * blockDim.x + threadIdx.x;
    if (e >= TOT_E) return;
    int src, dst;
    if (e < N_EDGES) { src = ei[e]; dst = ei[N_EDGES + e]; }
    else { src = e - N_EDGES; dst = src; }
    int pos = atomicAdd(&cursor[dst], 1);
    colidx[pos] = src;
}

// ---------------- weights: transpose-cast Ws[l][k][n] -> Wt[l][n][k] bf16 ----------------

__global__ void pack_w(const float* __restrict__ Ws, __hip_bfloat16* __restrict__ Wt) {
    int i = blockIdx.x * blockDim.x + threadIdx.x;
    if (i >= LAYERS * 512 * 128) return;
    int l = i / (512 * 128);
    int r = i % (512 * 128);
    int n = r / 128, k = r % 128;
    Wt[i] = __float2bfloat16(Ws[(size_t)l * 128 * 512 + k * 512 + n]);
}

// ---------------- fp32 tiled GEMM (input layer only): writes fp32 + bf16 ----------------

#define BM 64
#define BN 64
#define BK 16

__global__ __launch_bounds__(256) void gemm_bias(
    const float* __restrict__ A, const float* __restrict__ B,
    const float* __restrict__ bias, float* __restrict__ C,
    __hip_bfloat16* __restrict__ Cb, int M, int K, int Nc) {
    __shared__ float As[BK][BM + 4];
    __shared__ float Bs[BK][BN];
    int tid = threadIdx.x;
    int row0 = blockIdx.y * BM;
    int col0 = blockIdx.x * BN;
    int la_row = tid >> 2, la_k = (tid & 3) << 2;
    int lb_k = tid >> 4, lb_c = (tid & 15) << 2;
    int ty = tid >> 4, tx = tid & 15;
    float acc[4][4] = {};
    for (int kk = 0; kk < K; kk += BK) {
        int ar = row0 + la_row;
        float4 a4 = make_float4(0.f, 0.f, 0.f, 0.f);
        if (ar < M) a4 = *(const float4*)&A[(size_t)ar * K + kk + la_k];
        As[la_k + 0][la_row] = a4.x;
        As[la_k + 1][la_row] = a4.y;
        As[la_k + 2][la_row] = a4.z;
        As[la_k + 3][la_row] = a4.w;
        float4 b4 = *(const float4*)&B[(size_t)(kk + lb_k) * Nc + col0 + lb_c];
        *(float4*)&Bs[lb_k][lb_c] = b4;
        __syncthreads();
#pragma unroll
        for (int k = 0; k < BK; ++k) {
            float4 av = *(const float4*)&As[k][ty << 2];
            float4 bv = *(const float4*)&Bs[k][tx << 2];
            float a[4] = {av.x, av.y, av.z, av.w};
            float b[4] = {bv.x, bv.y, bv.z, bv.w};
#pragma unroll
            for (int i = 0; i < 4; ++i)
#pragma unroll
                for (int j = 0; j < 4; ++j)
                    acc[i][j] = fmaf(a[i], b[j], acc[i][j]);
        }
        __syncthreads();
    }
    int cbase = col0 + (tx << 2);
    float4 bv = make_float4(0.f, 0.f, 0.f, 0.f);
    if (bias) bv = *(const float4*)&bias[cbase];
#pragma unroll
    for (int i = 0; i < 4; ++i) {
        int r = row0 + (ty << 2) + i;
        if (r < M) {
            float4 o = make_float4(acc[i][0] + bv.x, acc[i][1] + bv.y,
                                   acc[i][2] + bv.z, acc[i][3] + bv.w);
            *(float4*)&C[(size_t)r * Nc + cbase] = o;
            if (Cb) {
                __hip_bfloat162 p0, p1;
                p0.x = __float2bfloat16(o.x); p0.y = __float2bfloat16(o.y);
                p1.x = __float2bfloat16(o.z); p1.y = __float2bfloat16(o.w);
                *(__hip_bfloat162*)&Cb[(size_t)r * Nc + cbase] = p0;
                *(__hip_bfloat162*)&Cb[(size_t)r * Nc + cbase + 2] = p1;
            }
        }
    }
}

// ---------------- bf16 MFMA GEMM: hproj[M][512] = h_bf16[M][128] @ W^T ----------------
// One block = 64 rows x all 512 cols; 4 waves, wave w = head w (64x128 tile).
// A tile staged to LDS via global_load_lds with both-sides XOR swizzle (c16 ^ (row&15)).

__global__ __launch_bounds__(256) void gemm_mfma(
    const __hip_bfloat16* __restrict__ A,   // [M][128]
    const __hip_bfloat16* __restrict__ Bt,  // [512][128]
    const float* __restrict__ att_s_l,      // [HEADS][128]
    const float* __restrict__ att_d_l,
    __hip_bfloat16* __restrict__ C,         // [M][512]
    float* __restrict__ a_s, float* __restrict__ a_d) {
    __shared__ __hip_bfloat16 As[64 * 128];   // 16KB, swizzled in 16B chunks
    __shared__ float sRed[HEADS][2][64];
    const int M_ = N_NODES;
    int tid = threadIdx.x;
    int lane = tid & 63, w = tid >> 6;        // w = head
    int lr = lane & 15, lg = lane >> 4;
    int row0 = blockIdx.x * 64;

    // stage A tile: 1024 chunks of 16B; LDS linear, global source pre-swizzled
#pragma unroll
    for (int it = 0; it < 4; ++it) {
        int chunk = it * 256 + tid;
        int row = chunk >> 4, c16 = chunk & 15;
        int sc = c16 ^ (row & 15);
        const __hip_bfloat16* src = A + (size_t)(row0 + row) * 128 + sc * 8;
        __builtin_amdgcn_global_load_lds(
            (const void __attribute__((address_space(1)))*)src,
            (void __attribute__((address_space(3)))*)(As + chunk * 8), 16, 0, 0);
    }
    __syncthreads();

    f32x4 acc[4][8] = {};
#pragma unroll
    for (int ks = 0; ks < 4; ++ks) {
        short8v b[8];
#pragma unroll
        for (int nf = 0; nf < 8; ++nf)
            b[nf] = *(const short8v*)&Bt[(size_t)(w * 128 + nf * 16 + lr) * 128 + ks * 32 + lg * 8];
        short8v a[4];
        int kc = ks * 4 + lg;
#pragma unroll
        for (int mf = 0; mf < 4; ++mf) {
            int rl = mf * 16 + lr;
            a[mf] = *(const short8v*)&As[(rl * 16 + (kc ^ (rl & 15))) * 8];
        }
#pragma unroll
        for (int mf = 0; mf < 4; ++mf)
#pragma unroll
            for (int nf = 0; nf < 8; ++nf)
                acc[mf][nf] = __builtin_amdgcn_mfma_f32_16x16x32_bf16(
                    a[mf], b[nf], acc[mf][nf], 0, 0, 0);
    }

    // store hproj bf16
#pragma unroll
    for (int mf = 0; mf < 4; ++mf) {
#pragma unroll
        for (int j = 0; j < 4; ++j) {
            int r = row0 + mf * 16 + lg * 4 + j;
            if (r < M_) {
#pragma unroll
                for (int nf = 0; nf < 8; ++nf) {
                    int c = w * 128 + nf * 16 + lr;
                    C[(size_t)r * 512 + c] = __float2bfloat16(acc[mf][nf][j]);
                }
            }
        }
    }

    // fused alpha: dot each output row (this head's 128 cols) with att vectors
    float asv[8], adv[8];
#pragma unroll
    for (int nf = 0; nf < 8; ++nf) {
        asv[nf] = att_s_l[w * HID + nf * 16 + lr];
        adv[nf] = att_d_l[w * HID + nf * 16 + lr];
    }
#pragma unroll
    for (int mf = 0; mf < 4; ++mf) {
#pragma unroll
        for (int j = 0; j < 4; ++j) {
            float ps = 0.f, pd = 0.f;
#pragma unroll
            for (int nf = 0; nf < 8; ++nf) {
                ps = fmaf(acc[mf][nf][j], asv[nf], ps);
                pd = fmaf(acc[mf][nf][j], adv[nf], pd);
            }
#pragma unroll
            for (int off = 1; off < 16; off <<= 1) {
                ps += __shfl_xor(ps, off);
                pd += __shfl_xor(pd, off);
            }
            if (lr == 0) {
                sRed[w][0][mf * 16 + lg * 4 + j] = ps;
                sRed[w][1][mf * 16 + lg * 4 + j] = pd;
            }
        }
    }
    __syncthreads();
    {
        int ww = tid & 3, rr = tid >> 2;      // 256 threads = 64 rows x 4 heads
        int gr = row0 + rr;
        if (gr < M_) {
            a_s[gr * HEADS + ww] = sRed[ww][0][rr];
            a_d[gr * HEADS + ww] = sRed[ww][1][rr];
        }
    }
}

// ---- fused per-dst-node: segment softmax + weighted bf16 gather-sum + head-mean
// ---- + bias + relu + residual + LayerNorm. One wave per node.
// ---- Logits computed ONCE in (edge,head)-parallel lane layout; p staged in LDS.

__global__ __launch_bounds__(256) void edge_kernel(
    const int* __restrict__ row_ptr, const int* __restrict__ colidx,
    const __hip_bfloat16* __restrict__ hproj, const float* __restrict__ a_s,
    const float* __restrict__ a_d, const float* __restrict__ conv_b,
    const float* __restrict__ ln_g, const float* __restrict__ ln_b,
    float* __restrict__ h, __hip_bfloat16* __restrict__ hb) {
    __shared__ float eLds[4][MAXD * 4];
    __shared__ int sLds[4][MAXD];
    int wv = threadIdx.x >> 6;
    int lane = threadIdx.x & 63;
    int n = blockIdx.x * 4 + wv;
    if (n >= N_NODES) return;
    int beg = row_ptr[n], end = row_ptr[n + 1];
    int deg = end - beg;

    float acc0[4] = {0.f, 0.f, 0.f, 0.f};
    float acc1[4] = {0.f, 0.f, 0.f, 0.f};
    float inv[4];

    if (deg <= MAXD) {
        int j = lane >> 2, hh = lane & 3;     // lane = j*4 + hh
        float adh = a_d[n * 4 + hh];
        // phase A: gather a_s once, logits to LDS, track per-lane max
        float mx = -3.4e38f;
        for (int c = 0; c < deg; c += 16) {
            int idx = c + j;
            float e = -3.4e38f;
            if (idx < deg) {
                int s = colidx[beg + idx];
                if (hh == 0) sLds[wv][idx] = s;
                e = a_s[s * 4 + hh] + adh;
                e = (e > 0.f) ? e : NEG_SLOPE * e;
            }
            eLds[wv][idx * 4 + hh] = e;
            mx = fmaxf(mx, e);
        }
        mx = fmaxf(mx, __shfl_xor(mx, 4));
        mx = fmaxf(mx, __shfl_xor(mx, 8));
        mx = fmaxf(mx, __shfl_xor(mx, 16));
        mx = fmaxf(mx, __shfl_xor(mx, 32));
        // phase B: exp in parallel layout, in-place p, partial denom
        float dsum = 0.f;
        for (int c = 0; c < deg; c += 16) {
            int idx = c + j;
            if (idx < deg) {
                float p = __expf(eLds[wv][idx * 4 + hh] - mx);
                eLds[wv][idx * 4 + hh] = p;
                dsum += p;
            }
        }
        dsum += __shfl_xor(dsum, 4);
        dsum += __shfl_xor(dsum, 8);
        dsum += __shfl_xor(dsum, 16);
        dsum += __shfl_xor(dsum, 32);
        // lane q (q<4) now holds denom for head q; broadcast all 4
#pragma unroll
        for (int q = 0; q < 4; ++q)
            inv[q] = 1.f / (__shfl(dsum, q) + 1e-16f);
        // phase C: accumulate, lane owns channels {2*lane, 2*lane+1}; 2-edge unroll
        int i = 0;
        for (; i + 1 < deg; i += 2) {
            int s0 = sLds[wv][i], s1 = sLds[wv][i + 1];
            float4 p0 = *(const float4*)&eLds[wv][i * 4];
            float4 p1 = *(const float4*)&eLds[wv][(i + 1) * 4];
            const unsigned int* h0 = (const unsigned int*)(hproj + (size_t)s0 * 512);
            const unsigned int* h1 = (const unsigned int*)(hproj + (size_t)s1 * 512);
            unsigned int u0[4], u1[4];
#pragma unroll
            for (int q = 0; q < 4; ++q) { u0[q] = h0[q * 64 + lane]; u1[q] = h1[q * 64 + lane]; }
            float pa0[4] = {p0.x, p0.y, p0.z, p0.w};
            float pa1[4] = {p1.x, p1.y, p1.z, p1.w};
#pragma unroll
            for (int q = 0; q < 4; ++q) {
                acc0[q] = fmaf(pa0[q], __uint_as_float(u0[q] << 16), acc0[q]);
                acc1[q] = fmaf(pa0[q], __uint_as_float(u0[q] & 0xffff0000u), acc1[q]);
                acc0[q] = fmaf(pa1[q], __uint_as_float(u1[q] << 16), acc0[q]);
                acc1[q] = fmaf(pa1[q], __uint_as_float(u1[q] & 0xffff0000u), acc1[q]);
            }
        }
        if (i < deg) {
            int s0 = sLds[wv][i];
            float4 p0 = *(const float4*)&eLds[wv][i * 4];
            const unsigned int* h0 = (const unsigned int*)(hproj + (size_t)s0 * 512);
            float pa0[4] = {p0.x, p0.y, p0.z, p0.w};
#pragma unroll
            for (int q = 0; q < 4; ++q) {
                unsigned int u = h0[q * 64 + lane];
                acc0[q] = fmaf(pa0[q], __uint_as_float(u << 16), acc0[q]);
                acc1[q] = fmaf(pa0[q], __uint_as_float(u & 0xffff0000u), acc1[q]);
            }
        }
    } else {
        // fallback (statistically never): original serial path
        float4 adv = *(const float4*)&a_d[n * 4];
        float ad[4] = {adv.x, adv.y, adv.z, adv.w};
        float m[4] = {-3.4e38f, -3.4e38f, -3.4e38f, -3.4e38f};
        for (int i = beg + lane; i < end; i += 64) {
            int s = colidx[i];
            float4 asv = *(const float4*)&a_s[s * 4];
            float av[4] = {asv.x, asv.y, asv.z, asv.w};
#pragma unroll
            for (int q = 0; q < 4; ++q) {
                float e = av[q] + ad[q];
                e = (e > 0.f) ? e : NEG_SLOPE * e;
                m[q] = fmaxf(m[q], e);
            }
        }
#pragma unroll
        for (int off = 32; off; off >>= 1)
#pragma unroll
            for (int q = 0; q < 4; ++q)
                m[q] = fmaxf(m[q], __shfl_xor(m[q], off));
        float denom[4] = {0.f, 0.f, 0.f, 0.f};
        for (int i = beg; i < end; ++i) {
            int s = colidx[i];
            float4 asv = *(const float4*)&a_s[s * 4];
            float av[4] = {asv.x, asv.y, asv.z, asv.w};
            float p[4];
#pragma unroll
            for (int q = 0; q < 4; ++q) {
                float e = av[q] + ad[q];
                e = (e > 0.f) ? e : NEG_SLOPE * e;
                p[q] = __expf(e - m[q]);
                denom[q] += p[q];
            }
            const unsigned int* hp = (const unsigned int*)(hproj + (size_t)s * 512);
#pragma unroll
            for (int q = 0; q < 4; ++q) {
                unsigned int u = hp[q * 64 + lane];
                acc0[q] = fmaf(p[q], __uint_as_float(u << 16), acc0[q]);
                acc1[q] = fmaf(p[q], __uint_as_float(u & 0xffff0000u), acc1[q]);
            }
        }
#pragma unroll
        for (int q = 0; q < 4; ++q) inv[q] = 1.f / (denom[q] + 1e-16f);
    }

    float r0 = 0.f, r1 = 0.f;
#pragma unroll
    for (int q = 0; q < 4; ++q) {
        r0 = fmaf(acc0[q], inv[q], r0);
        r1 = fmaf(acc1[q], inv[q], r1);
    }
    int c0 = lane * 2;
    r0 = 0.25f * r0 + conv_b[c0];
    r1 = 0.25f * r1 + conv_b[c0 + 1];
    r0 = fmaxf(r0, 0.f);
    r1 = fmaxf(r1, 0.f);
    float2 hold = *(const float2*)&h[(size_t)n * HID + c0];
    r0 += hold.x; r1 += hold.y;
    float s1 = r0 + r1;
#pragma unroll
    for (int off = 32; off; off >>= 1) s1 += __shfl_xor(s1, off);
    float mu = s1 * (1.f / HID);
    float d0 = r0 - mu, d1 = r1 - mu;
    float s2 = d0 * d0 + d1 * d1;
#pragma unroll
    for (int off = 32; off; off >>= 1) s2 += __shfl_xor(s2, off);
    float rstd = rsqrtf(s2 * (1.f / HID) + LN_EPS);
    float o0 = d0 * rstd * ln_g[c0] + ln_b[c0];
    float o1 = d1 * rstd * ln_g[c0 + 1] + ln_b[c0 + 1];
    *(float2*)&h[(size_t)n * HID + c0] = make_float2(o0, o1);
    __hip_bfloat162 hv;
    hv.x = __float2bfloat16(o0); hv.y = __float2bfloat16(o1);
    *(__hip_bfloat162*)&hb[(size_t)n * HID + c0] = hv;
}

// ---------------- global mean pool (batch is sorted) ----------------

__global__ __launch_bounds__(128) void pool_kernel(
    const float* __restrict__ h, const int* __restrict__ batch,
    float* __restrict__ pool_sum, int* __restrict__ pool_cnt) {
    int base = blockIdx.x * 64;
    int c = threadIdx.x;
    float acc = 0.f; int cur = -1;
    for (int i = 0; i < 64; ++i) {
        int n = base + i;
        if (n >= N_NODES) break;
        int g = batch[n];
        if (g != cur) {
            if (cur >= 0) atomicAdd(&pool_sum[cur * HID + c], acc);
            acc = 0.f; cur = g;
        }
        acc += h[(size_t)n * HID + c];
    }
    if (cur >= 0) atomicAdd(&pool_sum[cur * HID + c], acc);
    if (c == 0) {
        int run = 0; int curg = -1;
        for (int i = 0; i < 64; ++i) {
            int n = base + i;
            if (n >= N_NODES) break;
            int g = batch[n];
            if (g != curg) {
                if (curg >= 0) atomicAdd(&pool_cnt[curg], run);
                curg = g; run = 0;
            }
            run++;
        }
        if (curg >= 0) atomicAdd(&pool_cnt[curg], run);
    }
}

__global__ void finalize_kernel(const float* __restrict__ pool_sum,
                                const int* __restrict__ pool_cnt,
                                float* __restrict__ out) {
    int i = blockIdx.x * blockDim.x + threadIdx.x;
    if (i >= GRAPHS * HID) return;
    int g = i / HID;
    int c = pool_cnt[g];
    float cnt = (float)(c > 0 ? c : 1);
    out[i] = pool_sum[i] / cnt;
}

// ---------------- host ----------------

extern "C" void kernel_launch(void* const* d_in, const int* in_sizes, int n_in,
                              void* d_out, int out_size, void* d_ws, size_t ws_size,
                              hipStream_t stream) {
    const float* x      = (const float*)d_in[0];
    const int*   ei     = (const int*)d_in[1];
    const int*   batch  = (const int*)d_in[2];
    const float* W_in   = (const float*)d_in[3];
    const float* b_in   = (const float*)d_in[4];
    const float* Ws     = (const float*)d_in[5];
    const float* att_src= (const float*)d_in[6];
    const float* att_dst= (const float*)d_in[7];
    const float* conv_b = (const float*)d_in[8];
    const float* ln_g   = (const float*)d_in[9];
    const float* ln_b   = (const float*)d_in[10];
    float* out = (float*)d_out;

    char* ws = (char*)d_ws;
    size_t off = 0;
    auto alloc = [&](size_t bytes) -> void* {
        void* p = ws + off;
        off = (off + bytes + 255) & ~(size_t)255;
        return p;
    };
    float* h            = (float*)alloc((size_t)N_NODES * HID * 4);
    __hip_bfloat16* hb  = (__hip_bfloat16*)alloc((size_t)N_NODES * HID * 2);
    __hip_bfloat16* hpj = (__hip_bfloat16*)alloc((size_t)N_NODES * HEADS * HID * 2);
    __hip_bfloat16* Wt  = (__hip_bfloat16*)alloc((size_t)LAYERS * 512 * 128 * 2);
    float* a_s    = (float*)alloc((size_t)N_NODES * HEADS * 4);
    float* a_d    = (float*)alloc((size_t)N_NODES * HEADS * 4);
    int* row_ptr  = (int*)alloc((N_NODES + 1) * 4);
    int* cursor   = (int*)alloc(N_NODES * 4);
    int* colidx   = (int*)alloc((size_t)TOT_E * 4);
    int* counts   = (int*)alloc(N_NODES * 4);
    float* pool   = (float*)alloc(GRAPHS * HID * 4);
    int* cnt      = (int*)alloc(GRAPHS * 4);

    hipMemsetAsync(counts, 0, N_NODES * 4, stream);
    hipMemsetAsync(pool, 0, GRAPHS * HID * 4, stream);
    hipMemsetAsync(cnt, 0, GRAPHS * 4, stream);

    count_kernel<<<(TOT_E + 255) / 256, 256, 0, stream>>>(ei, counts);
    scan_kernel<<<1, 1024, 0, stream>>>(counts, row_ptr, cursor);
    fill_kernel<<<(TOT_E + 255) / 256, 256, 0, stream>>>(ei, cursor, colidx);
    pack_w<<<(LAYERS * 512 * 128 + 255) / 256, 256, 0, stream>>>(Ws, Wt);

    dim3 g_in(HID / BN, (N_NODES + BM - 1) / BM);
    gemm_bias<<<g_in, 256, 0, stream>>>(x, W_in, b_in, h, hb, N_NODES, IN_DIM, HID);

    for (int l = 0; l < LAYERS; ++l) {
        gemm_mfma<<<(N_NODES + 63) / 64, 256, 0, stream>>>(
            hb, Wt + (size_t)l * 512 * 128,
            att_src + (size_t)l * HEADS * HID, att_dst + (size_t)l * HEADS * HID,
            hpj, a_s, a_d);
        edge_kernel<<<(N_NODES + 3) / 4, 256, 0, stream>>>(
            row_ptr, colidx, hpj, a_s, a_d,
            conv_b + (size_t)l * HID, ln_g + (size_t)l * HID, ln_b + (size_t)l * HID,
            h, hb);
    }

    pool_kernel<<<(N_NODES + 63) / 64, 128, 0, stream>>>(h, batch, pool, cnt);
    finalize_kernel<<<(GRAPHS * HID + 255) / 256, 256, 0, stream>>>(pool, cnt, out);
}

// Round 4
// 334.579 us; speedup vs baseline: 1.8146x; 1.0125x over previous
//
#include <hip/hip_runtime.h>
#include <hip/hip_bf16.h>
#include <math.h>

#define N_NODES 20000
#define N_EDGES 320000
#define IN_DIM 64
#define HID 128
#define HEADS 4
#define LAYERS 3
#define GRAPHS 64
#define TOT_E (N_EDGES + N_NODES)
#define NEG_SLOPE 0.2f
#define LN_EPS 1e-5f
#define MAXD 96   // fast-path max degree; fallback below

typedef __attribute__((ext_vector_type(8))) short short8v;
typedef __attribute__((ext_vector_type(4))) float f32x4;

// ---------------- CSR build (by dst), rebuilt deterministically every call ----------------

__global__ void count_kernel(const int* __restrict__ ei, int* __restrict__ counts) {
    int e = blockIdx.x * blockDim.x + threadIdx.x;
    if (e >= TOT_E) return;
    int dst = (e < N_EDGES) ? ei[N_EDGES + e] : (e - N_EDGES);
    atomicAdd(&counts[dst], 1);
}

__global__ void scan_kernel(const int* __restrict__ counts, int* __restrict__ row_ptr,
                            int* __restrict__ cursor) {
    __shared__ int part[1024];
    int tid = threadIdx.x;
    const int per = (N_NODES + 1023) / 1024;  // 20
    int start = tid * per;
    int end = start + per; if (end > N_NODES) end = N_NODES;
    int s = 0;
    for (int i = start; i < end; ++i) s += counts[i];
    part[tid] = s;
    __syncthreads();
    for (int off = 1; off < 1024; off <<= 1) {
        int v = (tid >= off) ? part[tid - off] : 0;
        __syncthreads();
        part[tid] += v;
        __syncthreads();
    }
    int run = (tid > 0) ? part[tid - 1] : 0;
    for (int i = start; i < end; ++i) {
        row_ptr[i] = run; cursor[i] = run; run += counts[i];
    }
    if (tid == 1023) row_ptr[N_NODES] = part[1023];
}

__global__ void fill_kernel(const int* __restrict__ ei, int* __restrict__ cursor,
                            int* __restrict__ colidx) {
    int e = blockIdx.x * blockDim.x + threadIdx.x;
    if (e >= TOT_E) return;
    int src, dst;
    if (e < N_EDGES) { src = ei[e]; dst = ei[N_EDGES + e]; }
    else { src = e - N_EDGES; dst = src; }
    int pos = atomicAdd(&cursor[dst], 1);
    colidx[pos] = src;
}

// ---------------- zero scratch (counts + pool + cnt) in one dispatch ----------------

__global__ void zero_kernel(int* __restrict__ counts, float* __restrict__ pool,
                            int* __restrict__ cnt) {
    int i = blockIdx.x * blockDim.x + threadIdx.x;
    if (i < N_NODES) { counts[i] = 0; return; }
    i -= N_NODES;
    if (i < GRAPHS * HID) { pool[i] = 0.f; return; }
    i -= GRAPHS * HID;
    if (i < GRAPHS) cnt[i] = 0;
}

// ------------- pack: Ws->Wt (transposed bf16), W_in->Wt_in (transposed bf16), x->xb -------------

#define NW (LAYERS * 512 * 128)
#define NWIN (HID * IN_DIM)
#define NX (N_NODES * IN_DIM)

__global__ void pack_all(const float* __restrict__ Ws, const float* __restrict__ W_in,
                         const float* __restrict__ x, __hip_bfloat16* __restrict__ Wt,
                         __hip_bfloat16* __restrict__ Wt_in, __hip_bfloat16* __restrict__ xb) {
    int i = blockIdx.x * blockDim.x + threadIdx.x;
    if (i < NW) {
        int l = i / (512 * 128);
        int r = i % (512 * 128);
        int n = r / 128, k = r % 128;
        Wt[i] = __float2bfloat16(Ws[(size_t)l * 128 * 512 + k * 512 + n]);
    } else if (i < NW + NWIN) {
        int r = i - NW;                 // Wt_in[n][k], n<128, k<64
        int n = r / 64, k = r % 64;
        Wt_in[r] = __float2bfloat16(W_in[k * 128 + n]);
    } else if (i < NW + NWIN + NX) {
        int r = i - NW - NWIN;
        xb[r] = __float2bfloat16(x[r]);
    }
}

// ---------------- input layer MFMA: h[M][128] = xb[M][64] @ W_in + b_in ----------------

__global__ __launch_bounds__(256) void gemm_in(
    const __hip_bfloat16* __restrict__ Ax,   // [M][64]
    const __hip_bfloat16* __restrict__ Bt,   // [128][64]
    const float* __restrict__ bias,          // [128]
    float* __restrict__ h, __hip_bfloat16* __restrict__ hb) {
    __shared__ __hip_bfloat16 As[64 * 64];    // 8KB, swizzled 16B chunks
    const int M_ = N_NODES;
    int tid = threadIdx.x;
    int lane = tid & 63, w = tid >> 6;
    int lr = lane & 15, lg = lane >> 4;
    int row0 = blockIdx.x * 64;
#pragma unroll
    for (int it = 0; it < 2; ++it) {
        int chunk = it * 256 + tid;
        int row = chunk >> 3, c8 = chunk & 7;
        int sc = c8 ^ (row & 7);
        int gr = row0 + row; if (gr >= M_) gr = M_ - 1;
        const __hip_bfloat16* src = Ax + (size_t)gr * 64 + sc * 8;
        __builtin_amdgcn_global_load_lds(
            (const void __attribute__((address_space(1)))*)src,
            (void __attribute__((address_space(3)))*)(As + chunk * 8), 16, 0, 0);
    }
    __syncthreads();

    f32x4 acc[4][2] = {};
#pragma unroll
    for (int ks = 0; ks < 2; ++ks) {
        short8v b[2];
#pragma unroll
        for (int nf = 0; nf < 2; ++nf)
            b[nf] = *(const short8v*)&Bt[(size_t)(w * 32 + nf * 16 + lr) * 64 + ks * 32 + lg * 8];
        short8v a[4];
        int kc = ks * 4 + lg;
#pragma unroll
        for (int mf = 0; mf < 4; ++mf) {
            int rl = mf * 16 + lr;
            a[mf] = *(const short8v*)&As[(rl * 8 + (kc ^ (rl & 7))) * 8];
        }
#pragma unroll
        for (int mf = 0; mf < 4; ++mf)
#pragma unroll
            for (int nf = 0; nf < 2; ++nf)
                acc[mf][nf] = __builtin_amdgcn_mfma_f32_16x16x32_bf16(
                    a[mf], b[nf], acc[mf][nf], 0, 0, 0);
    }
#pragma unroll
    for (int mf = 0; mf < 4; ++mf) {
#pragma unroll
        for (int jj = 0; jj < 4; ++jj) {
            int r = row0 + mf * 16 + lg * 4 + jj;
            if (r < M_) {
#pragma unroll
                for (int nf = 0; nf < 2; ++nf) {
                    int c = w * 32 + nf * 16 + lr;
                    float v = acc[mf][nf][jj] + bias[c];
                    h[(size_t)r * HID + c] = v;
                    hb[(size_t)r * HID + c] = __float2bfloat16(v);
                }
            }
        }
    }
}

// ---------------- bf16 MFMA GEMM: hproj[M][512] = h_bf16[M][128] @ W^T ----------------
// One block = 64 rows x all 512 cols; 4 waves, wave w = head w (64x128 tile).

__global__ __launch_bounds__(256) void gemm_mfma(
    const __hip_bfloat16* __restrict__ A,   // [M][128]
    const __hip_bfloat16* __restrict__ Bt,  // [512][128]
    const float* __restrict__ att_s_l,      // [HEADS][128]
    const float* __restrict__ att_d_l,
    __hip_bfloat16* __restrict__ C,         // [M][512]
    float* __restrict__ a_s, float* __restrict__ a_d) {
    __shared__ __hip_bfloat16 As[64 * 128];   // 16KB, swizzled in 16B chunks
    __shared__ float sRed[HEADS][2][64];
    const int M_ = N_NODES;
    int tid = threadIdx.x;
    int lane = tid & 63, w = tid >> 6;        // w = head
    int lr = lane & 15, lg = lane >> 4;
    int row0 = blockIdx.x * 64;

#pragma unroll
    for (int it = 0; it < 4; ++it) {
        int chunk = it * 256 + tid;
        int row = chunk >> 4, c16 = chunk & 15;
        int sc = c16 ^ (row & 15);
        const __hip_bfloat16* src = A + (size_t)(row0 + row) * 128 + sc * 8;
        __builtin_amdgcn_global_load_lds(
            (const void __attribute__((address_space(1)))*)src,
            (void __attribute__((address_space(3)))*)(As + chunk * 8), 16, 0, 0);
    }
    __syncthreads();

    f32x4 acc[4][8] = {};
#pragma unroll
    for (int ks = 0; ks < 4; ++ks) {
        short8v b[8];
#pragma unroll
        for (int nf = 0; nf < 8; ++nf)
            b[nf] = *(const short8v*)&Bt[(size_t)(w * 128 + nf * 16 + lr) * 128 + ks * 32 + lg * 8];
        short8v a[4];
        int kc = ks * 4 + lg;
#pragma unroll
        for (int mf = 0; mf < 4; ++mf) {
            int rl = mf * 16 + lr;
            a[mf] = *(const short8v*)&As[(rl * 16 + (kc ^ (rl & 15))) * 8];
        }
#pragma unroll
        for (int mf = 0; mf < 4; ++mf)
#pragma unroll
            for (int nf = 0; nf < 8; ++nf)
                acc[mf][nf] = __builtin_amdgcn_mfma_f32_16x16x32_bf16(
                    a[mf], b[nf], acc[mf][nf], 0, 0, 0);
    }

#pragma unroll
    for (int mf = 0; mf < 4; ++mf) {
#pragma unroll
        for (int j = 0; j < 4; ++j) {
            int r = row0 + mf * 16 + lg * 4 + j;
            if (r < M_) {
#pragma unroll
                for (int nf = 0; nf < 8; ++nf) {
                    int c = w * 128 + nf * 16 + lr;
                    C[(size_t)r * 512 + c] = __float2bfloat16(acc[mf][nf][j]);
                }
            }
        }
    }

    float asv[8], adv[8];
#pragma unroll
    for (int nf = 0; nf < 8; ++nf) {
        asv[nf] = att_s_l[w * HID + nf * 16 + lr];
        adv[nf] = att_d_l[w * HID + nf * 16 + lr];
    }
#pragma unroll
    for (int mf = 0; mf < 4; ++mf) {
#pragma unroll
        for (int j = 0; j < 4; ++j) {
            float ps = 0.f, pd = 0.f;
#pragma unroll
            for (int nf = 0; nf < 8; ++nf) {
                ps = fmaf(acc[mf][nf][j], asv[nf], ps);
                pd = fmaf(acc[mf][nf][j], adv[nf], pd);
            }
#pragma unroll
            for (int off = 1; off < 16; off <<= 1) {
                ps += __shfl_xor(ps, off);
                pd += __shfl_xor(pd, off);
            }
            if (lr == 0) {
                sRed[w][0][mf * 16 + lg * 4 + j] = ps;
                sRed[w][1][mf * 16 + lg * 4 + j] = pd;
            }
        }
    }
    __syncthreads();
    {
        int ww = tid & 3, rr = tid >> 2;
        int gr = row0 + rr;
        if (gr < M_) {
            a_s[gr * HEADS + ww] = sRed[ww][0][rr];
            a_d[gr * HEADS + ww] = sRed[ww][1][rr];
        }
    }
}

// ---- fused per-dst-node: segment softmax + weighted bf16 gather-sum + head-mean
// ---- + bias + relu + residual + LayerNorm. One wave per node.
// ---- Phase C layout: lane = head(l>>4) x 16B-block(l&15); ONE dwordx4 per edge.

__global__ __launch_bounds__(256) void edge_kernel(
    const int* __restrict__ row_ptr, const int* __restrict__ colidx,
    const __hip_bfloat16* __restrict__ hproj, const float* __restrict__ a_s,
    const float* __restrict__ a_d, const float* __restrict__ conv_b,
    const float* __restrict__ ln_g, const float* __restrict__ ln_b,
    float* __restrict__ h, __hip_bfloat16* __restrict__ hb) {
    __shared__ float eLds[4][MAXD * 4];
    __shared__ int sLds[4][MAXD];
    int wv = threadIdx.x >> 6;
    int lane = threadIdx.x & 63;
    int n = blockIdx.x * 4 + wv;
    if (n >= N_NODES) return;
    int beg = row_ptr[n], end = row_ptr[n + 1];
    int deg = end - beg;

    int hh = lane >> 4;       // head owned in phase C / epilogue
    int j  = lane & 15;       // 16B channel block within head
    float acc[8] = {0.f, 0.f, 0.f, 0.f, 0.f, 0.f, 0.f, 0.f};
    float inv_own;
    const __hip_bfloat16* hbase = hproj + hh * 128 + j * 8;

    if (deg <= MAXD) {
        // phase A: logits once, edge-parallel (lane = ja*4 + ha)
        int ja = lane >> 2, ha = lane & 3;
        float adh = a_d[n * 4 + ha];
        float mx = -3.4e38f;
        for (int c = 0; c < deg; c += 16) {
            int idx = c + ja;
            float e = -3.4e38f;
            if (idx < deg) {
                int s = colidx[beg + idx];
                if (ha == 0) sLds[wv][idx] = s;
                e = a_s[s * 4 + ha] + adh;
                e = (e > 0.f) ? e : NEG_SLOPE * e;
            }
            eLds[wv][idx * 4 + ha] = e;
            mx = fmaxf(mx, e);
        }
        mx = fmaxf(mx, __shfl_xor(mx, 4));
        mx = fmaxf(mx, __shfl_xor(mx, 8));
        mx = fmaxf(mx, __shfl_xor(mx, 16));
        mx = fmaxf(mx, __shfl_xor(mx, 32));
        // phase B: exp in parallel layout, in-place p, denom
        float dsum = 0.f;
        for (int c = 0; c < deg; c += 16) {
            int idx = c + ja;
            if (idx < deg) {
                float p = __expf(eLds[wv][idx * 4 + ha] - mx);
                eLds[wv][idx * 4 + ha] = p;
                dsum += p;
            }
        }
        dsum += __shfl_xor(dsum, 4);
        dsum += __shfl_xor(dsum, 8);
        dsum += __shfl_xor(dsum, 16);
        dsum += __shfl_xor(dsum, 32);
        float dh = __shfl(dsum, hh);            // lane q<4 holds head q's denom
        inv_own = 1.f / (dh + 1e-16f);
        // phase C: one dwordx4 gather per edge
        int i = 0;
        for (; i + 1 < deg; i += 2) {
            int s0 = sLds[wv][i], s1 = sLds[wv][i + 1];
            float p0 = eLds[wv][i * 4 + hh];
            float p1 = eLds[wv][(i + 1) * 4 + hh];
            uint4 u0 = *(const uint4*)(hbase + (size_t)s0 * 512);
            uint4 u1 = *(const uint4*)(hbase + (size_t)s1 * 512);
            acc[0] = fmaf(p0, __uint_as_float(u0.x << 16), acc[0]);
            acc[1] = fmaf(p0, __uint_as_float(u0.x & 0xffff0000u), acc[1]);
            acc[2] = fmaf(p0, __uint_as_float(u0.y << 16), acc[2]);
            acc[3] = fmaf(p0, __uint_as_float(u0.y & 0xffff0000u), acc[3]);
            acc[4] = fmaf(p0, __uint_as_float(u0.z << 16), acc[4]);
            acc[5] = fmaf(p0, __uint_as_float(u0.z & 0xffff0000u), acc[5]);
            acc[6] = fmaf(p0, __uint_as_float(u0.w << 16), acc[6]);
            acc[7] = fmaf(p0, __uint_as_float(u0.w & 0xffff0000u), acc[7]);
            acc[0] = fmaf(p1, __uint_as_float(u1.x << 16), acc[0]);
            acc[1] = fmaf(p1, __uint_as_float(u1.x & 0xffff0000u), acc[1]);
            acc[2] = fmaf(p1, __uint_as_float(u1.y << 16), acc[2]);
            acc[3] = fmaf(p1, __uint_as_float(u1.y & 0xffff0000u), acc[3]);
            acc[4] = fmaf(p1, __uint_as_float(u1.z << 16), acc[4]);
            acc[5] = fmaf(p1, __uint_as_float(u1.z & 0xffff0000u), acc[5]);
            acc[6] = fmaf(p1, __uint_as_float(u1.w << 16), acc[6]);
            acc[7] = fmaf(p1, __uint_as_float(u1.w & 0xffff0000u), acc[7]);
        }
        if (i < deg) {
            int s0 = sLds[wv][i];
            float p0 = eLds[wv][i * 4 + hh];
            uint4 u0 = *(const uint4*)(hbase + (size_t)s0 * 512);
            acc[0] = fmaf(p0, __uint_as_float(u0.x << 16), acc[0]);
            acc[1] = fmaf(p0, __uint_as_float(u0.x & 0xffff0000u), acc[1]);
            acc[2] = fmaf(p0, __uint_as_float(u0.y << 16), acc[2]);
            acc[3] = fmaf(p0, __uint_as_float(u0.y & 0xffff0000u), acc[3]);
            acc[4] = fmaf(p0, __uint_as_float(u0.z << 16), acc[4]);
            acc[5] = fmaf(p0, __uint_as_float(u0.z & 0xffff0000u), acc[5]);
            acc[6] = fmaf(p0, __uint_as_float(u0.w << 16), acc[6]);
            acc[7] = fmaf(p0, __uint_as_float(u0.w & 0xffff0000u), acc[7]);
        }
    } else {
        // fallback (statistically never): own-head two-pass
        float adh = a_d[n * 4 + hh];
        float m = -3.4e38f;
        for (int i = beg + j; i < end; i += 16) {
            int s = colidx[i];
            float e = a_s[s * 4 + hh] + adh;
            e = (e > 0.f) ? e : NEG_SLOPE * e;
            m = fmaxf(m, e);
        }
        m = fmaxf(m, __shfl_xor(m, 1));
        m = fmaxf(m, __shfl_xor(m, 2));
        m = fmaxf(m, __shfl_xor(m, 4));
        m = fmaxf(m, __shfl_xor(m, 8));
        float denom = 0.f;
        for (int i = beg; i < end; ++i) {
            int s = colidx[i];
            float e = a_s[s * 4 + hh] + adh;
            e = (e > 0.f) ? e : NEG_SLOPE * e;
            float p = __expf(e - m);
            denom += p;
            uint4 u0 = *(const uint4*)(hbase + (size_t)s * 512);
            acc[0] = fmaf(p, __uint_as_float(u0.x << 16), acc[0]);
            acc[1] = fmaf(p, __uint_as_float(u0.x & 0xffff0000u), acc[1]);
            acc[2] = fmaf(p, __uint_as_float(u0.y << 16), acc[2]);
            acc[3] = fmaf(p, __uint_as_float(u0.y & 0xffff0000u), acc[3]);
            acc[4] = fmaf(p, __uint_as_float(u0.z << 16), acc[4]);
            acc[5] = fmaf(p, __uint_as_float(u0.z & 0xffff0000u), acc[5]);
            acc[6] = fmaf(p, __uint_as_float(u0.w << 16), acc[6]);
            acc[7] = fmaf(p, __uint_as_float(u0.w & 0xffff0000u), acc[7]);
        }
        inv_own = 1.f / (denom + 1e-16f);
    }

    // epilogue: r[k] = per-head result; sum heads via xor 16,32; then bias+relu+res+LN
    float r[8];
#pragma unroll
    for (int k = 0; k < 8; ++k) r[k] = acc[k] * inv_own;
#pragma unroll
    for (int k = 0; k < 8; ++k) {
        r[k] += __shfl_xor(r[k], 16);
        r[k] += __shfl_xor(r[k], 32);
    }
    int c0 = j * 8;
    float4 cb0 = *(const float4*)&conv_b[c0];
    float4 cb1 = *(const float4*)&conv_b[c0 + 4];
    float4 h0 = *(const float4*)&h[(size_t)n * HID + c0];
    float4 h1 = *(const float4*)&h[(size_t)n * HID + c0 + 4];
    float cb[8] = {cb0.x, cb0.y, cb0.z, cb0.w, cb1.x, cb1.y, cb1.z, cb1.w};
    float hr[8] = {h0.x, h0.y, h0.z, h0.w, h1.x, h1.y, h1.z, h1.w};
#pragma unroll
    for (int k = 0; k < 8; ++k) {
        r[k] = fmaxf(0.25f * r[k] + cb[k], 0.f) + hr[k];
    }
    float s1 = 0.f;
#pragma unroll
    for (int k = 0; k < 8; ++k) s1 += r[k];
#pragma unroll
    for (int off = 1; off < 64; off <<= 1) s1 += __shfl_xor(s1, off);
    float mu = s1 * (1.f / (4.f * HID));       // 4x redundancy across head groups
    float s2 = 0.f;
#pragma unroll
    for (int k = 0; k < 8; ++k) {
        r[k] -= mu;
        s2 += r[k] * r[k];
    }
#pragma unroll
    for (int off = 1; off < 64; off <<= 1) s2 += __shfl_xor(s2, off);
    float rstd = rsqrtf(s2 * (1.f / (4.f * HID)) + LN_EPS);
    float4 g0 = *(const float4*)&ln_g[c0];
    float4 g1 = *(const float4*)&ln_g[c0 + 4];
    float4 b0 = *(const float4*)&ln_b[c0];
    float4 b1 = *(const float4*)&ln_b[c0 + 4];
    float gg[8] = {g0.x, g0.y, g0.z, g0.w, g1.x, g1.y, g1.z, g1.w};
    float bb[8] = {b0.x, b0.y, b0.z, b0.w, b1.x, b1.y, b1.z, b1.w};
    float o[8];
#pragma unroll
    for (int k = 0; k < 8; ++k) o[k] = r[k] * rstd * gg[k] + bb[k];
    if (hh == 0) {
        *(float4*)&h[(size_t)n * HID + c0] = make_float4(o[0], o[1], o[2], o[3]);
        *(float4*)&h[(size_t)n * HID + c0 + 4] = make_float4(o[4], o[5], o[6], o[7]);
        __hip_bfloat162 q[4];
#pragma unroll
        for (int k = 0; k < 4; ++k) {
            q[k].x = __float2bfloat16(o[2 * k]);
            q[k].y = __float2bfloat16(o[2 * k + 1]);
        }
        *(uint4*)&hb[(size_t)n * HID + c0] = *(uint4*)q;
    }
}

// ---------------- global mean pool (batch is sorted) ----------------

__global__ __launch_bounds__(128) void pool_kernel(
    const float* __restrict__ h, const int* __restrict__ batch,
    float* __restrict__ pool_sum, int* __restrict__ pool_cnt) {
    int base = blockIdx.x * 64;
    int c = threadIdx.x;
    float acc = 0.f; int cur = -1;
    for (int i = 0; i < 64; ++i) {
        int n = base + i;
        if (n >= N_NODES) break;
        int g = batch[n];
        if (g != cur) {
            if (cur >= 0) atomicAdd(&pool_sum[cur * HID + c], acc);
            acc = 0.f; cur = g;
        }
        acc += h[(size_t)n * HID + c];
    }
    if (cur >= 0) atomicAdd(&pool_sum[cur * HID + c], acc);
    if (c == 0) {
        int run = 0; int curg = -1;
        for (int i = 0; i < 64; ++i) {
            int n = base + i;
            if (n >= N_NODES) break;
            int g = batch[n];
            if (g != curg) {
                if (curg >= 0) atomicAdd(&pool_cnt[curg], run);
                curg = g; run = 0;
            }
            run++;
        }
        if (curg >= 0) atomicAdd(&pool_cnt[curg], run);
    }
}

__global__ void finalize_kernel(const float* __restrict__ pool_sum,
                                const int* __restrict__ pool_cnt,
                                float* __restrict__ out) {
    int i = blockIdx.x * blockDim.x + threadIdx.x;
    if (i >= GRAPHS * HID) return;
    int g = i / HID;
    int c = pool_cnt[g];
    float cnt = (float)(c > 0 ? c : 1);
    out[i] = pool_sum[i] / cnt;
}

// ---------------- host ----------------

extern "C" void kernel_launch(void* const* d_in, const int* in_sizes, int n_in,
                              void* d_out, int out_size, void* d_ws, size_t ws_size,
                              hipStream_t stream) {
    const float* x      = (const float*)d_in[0];
    const int*   ei     = (const int*)d_in[1];
    const int*   batch  = (const int*)d_in[2];
    const float* W_in   = (const float*)d_in[3];
    const float* b_in   = (const float*)d_in[4];
    const float* Ws     = (const float*)d_in[5];
    const float* att_src= (const float*)d_in[6];
    const float* att_dst= (const float*)d_in[7];
    const float* conv_b = (const float*)d_in[8];
    const float* ln_g   = (const float*)d_in[9];
    const float* ln_b   = (const float*)d_in[10];
    float* out = (float*)d_out;

    char* ws = (char*)d_ws;
    size_t off = 0;
    auto alloc = [&](size_t bytes) -> void* {
        void* p = ws + off;
        off = (off + bytes + 255) & ~(size_t)255;
        return p;
    };
    float* h            = (float*)alloc((size_t)N_NODES * HID * 4);
    __hip_bfloat16* hb  = (__hip_bfloat16*)alloc((size_t)N_NODES * HID * 2);
    __hip_bfloat16* hpj = (__hip_bfloat16*)alloc((size_t)N_NODES * HEADS * HID * 2);
    __hip_bfloat16* Wt  = (__hip_bfloat16*)alloc((size_t)LAYERS * 512 * 128 * 2);
    __hip_bfloat16* Wti = (__hip_bfloat16*)alloc((size_t)HID * IN_DIM * 2);
    __hip_bfloat16* xb  = (__hip_bfloat16*)alloc((size_t)N_NODES * IN_DIM * 2);
    float* a_s    = (float*)alloc((size_t)N_NODES * HEADS * 4);
    float* a_d    = (float*)alloc((size_t)N_NODES * HEADS * 4);
    int* row_ptr  = (int*)alloc((N_NODES + 1) * 4);
    int* cursor   = (int*)alloc(N_NODES * 4);
    int* colidx   = (int*)alloc((size_t)TOT_E * 4);
    int* counts   = (int*)alloc(N_NODES * 4);
    float* pool   = (float*)alloc(GRAPHS * HID * 4);
    int* cnt      = (int*)alloc(GRAPHS * 4);

    zero_kernel<<<(N_NODES + GRAPHS * HID + GRAPHS + 255) / 256, 256, 0, stream>>>(
        counts, pool, cnt);
    count_kernel<<<(TOT_E + 255) / 256, 256, 0, stream>>>(ei, counts);
    scan_kernel<<<1, 1024, 0, stream>>>(counts, row_ptr, cursor);
    fill_kernel<<<(TOT_E + 255) / 256, 256, 0, stream>>>(ei, cursor, colidx);
    pack_all<<<(NW + NWIN + NX + 255) / 256, 256, 0, stream>>>(Ws, W_in, x, Wt, Wti, xb);

    gemm_in<<<(N_NODES + 63) / 64, 256, 0, stream>>>(xb, Wti, b_in, h, hb);

    for (int l = 0; l < LAYERS; ++l) {
        gemm_mfma<<<(N_NODES + 63) / 64, 256, 0, stream>>>(
            hb, Wt + (size_t)l * 512 * 128,
            att_src + (size_t)l * HEADS * HID, att_dst + (size_t)l * HEADS * HID,
            hpj, a_s, a_d);
        edge_kernel<<<(N_NODES + 3) / 4, 256, 0, stream>>>(
            row_ptr, colidx, hpj, a_s, a_d,
            conv_b + (size_t)l * HID, ln_g + (size_t)l * HID, ln_b + (size_t)l * HID,
            h, hb);
    }

    pool_kernel<<<(N_NODES + 63) / 64, 128, 0, stream>>>(h, batch, pool, cnt);
    finalize_kernel<<<(GRAPHS * HID + 255) / 256, 256, 0, stream>>>(pool, cnt, out);
}

// Round 5
// 333.382 us; speedup vs baseline: 1.8211x; 1.0036x over previous
//
#include <hip/hip_runtime.h>
#include <hip/hip_bf16.h>
#include <math.h>

#define N_NODES 20000
#define N_EDGES 320000
#define IN_DIM 64
#define HID 128
#define HEADS 4
#define LAYERS 3
#define GRAPHS 64
#define TOT_E (N_EDGES + N_NODES)
#define NEG_SLOPE 0.2f
#define LN_EPS 1e-5f
#define MAXD 96   // fast-path max degree; fallback below

typedef __attribute__((ext_vector_type(8))) short short8v;
typedef __attribute__((ext_vector_type(4))) float f32x4;

__device__ __forceinline__ float blo(unsigned int u) { return __uint_as_float(u << 16); }
__device__ __forceinline__ float bhi(unsigned int u) { return __uint_as_float(u & 0xffff0000u); }

// ---------------- CSR build (by dst), rebuilt deterministically every call ----------------

__global__ void count_kernel(const int* __restrict__ ei, int* __restrict__ counts) {
    int e = blockIdx.x * blockDim.x + threadIdx.x;
    if (e >= TOT_E) return;
    int dst = (e < N_EDGES) ? ei[N_EDGES + e] : (e - N_EDGES);
    atomicAdd(&counts[dst], 1);
}

__global__ void scan_kernel(const int* __restrict__ counts, int* __restrict__ row_ptr,
                            int* __restrict__ cursor) {
    __shared__ int part[1024];
    int tid = threadIdx.x;
    const int per = (N_NODES + 1023) / 1024;  // 20 (divides: threads 0..999 full, rest empty)
    int start = tid * per;
    int end = start + per; if (end > N_NODES) end = N_NODES;
    int s = 0;
    if (end == start + 20) {
        const int4* c4 = (const int4*)(counts + start);
#pragma unroll
        for (int q = 0; q < 5; ++q) {
            int4 v = c4[q];
            s += v.x + v.y + v.z + v.w;
        }
    } else {
        for (int i = start; i < end; ++i) s += counts[i];
    }
    part[tid] = s;
    __syncthreads();
    for (int off = 1; off < 1024; off <<= 1) {
        int v = (tid >= off) ? part[tid - off] : 0;
        __syncthreads();
        part[tid] += v;
        __syncthreads();
    }
    int run = (tid > 0) ? part[tid - 1] : 0;
    for (int i = start; i < end; ++i) {
        row_ptr[i] = run; cursor[i] = run; run += counts[i];
    }
    if (tid == 1023) row_ptr[N_NODES] = part[1023];
}

__global__ void fill_kernel(const int* __restrict__ ei, int* __restrict__ cursor,
                            int* __restrict__ colidx) {
    int e = blockIdx.x * blockDim.x + threadIdx.x;
    if (e >= TOT_E) return;
    int src, dst;
    if (e < N_EDGES) { src = ei[e]; dst = ei[N_EDGES + e]; }
    else { src = e - N_EDGES; dst = src; }
    int pos = atomicAdd(&cursor[dst], 1);
    colidx[pos] = src;
}

// ---------------- zero scratch (counts + pool + cnt) in one dispatch ----------------

__global__ void zero_kernel(int* __restrict__ counts, float* __restrict__ pool,
                            int* __restrict__ cnt) {
    int i = blockIdx.x * blockDim.x + threadIdx.x;
    if (i < N_NODES) { counts[i] = 0; return; }
    i -= N_NODES;
    if (i < GRAPHS * HID) { pool[i] = 0.f; return; }
    i -= GRAPHS * HID;
    if (i < GRAPHS) cnt[i] = 0;
}

// ------------- pack: Ws->Wt (transposed bf16), W_in->Wt_in (transposed bf16), x->xb -------------

#define NW (LAYERS * 512 * 128)
#define NWIN (HID * IN_DIM)
#define NX (N_NODES * IN_DIM)

__global__ void pack_all(const float* __restrict__ Ws, const float* __restrict__ W_in,
                         const float* __restrict__ x, __hip_bfloat16* __restrict__ Wt,
                         __hip_bfloat16* __restrict__ Wt_in, __hip_bfloat16* __restrict__ xb) {
    int i = blockIdx.x * blockDim.x + threadIdx.x;
    if (i < NW) {
        int l = i / (512 * 128);
        int r = i % (512 * 128);
        int n = r / 128, k = r % 128;
        Wt[i] = __float2bfloat16(Ws[(size_t)l * 128 * 512 + k * 512 + n]);
    } else if (i < NW + NWIN) {
        int r = i - NW;                 // Wt_in[n][k], n<128, k<64
        int n = r / 64, k = r % 64;
        Wt_in[r] = __float2bfloat16(W_in[k * 128 + n]);
    } else if (i < NW + NWIN + NX) {
        int r = i - NW - NWIN;
        xb[r] = __float2bfloat16(x[r]);
    }
}

// ---------------- input layer MFMA: h[M][128] = xb[M][64] @ W_in + b_in ----------------

__global__ __launch_bounds__(256) void gemm_in(
    const __hip_bfloat16* __restrict__ Ax,   // [M][64]
    const __hip_bfloat16* __restrict__ Bt,   // [128][64]
    const float* __restrict__ bias,          // [128]
    float* __restrict__ h, __hip_bfloat16* __restrict__ hb) {
    __shared__ __hip_bfloat16 As[64 * 64];    // 8KB, swizzled 16B chunks
    const int M_ = N_NODES;
    int tid = threadIdx.x;
    int lane = tid & 63, w = tid >> 6;
    int lr = lane & 15, lg = lane >> 4;
    int row0 = blockIdx.x * 64;
#pragma unroll
    for (int it = 0; it < 2; ++it) {
        int chunk = it * 256 + tid;
        int row = chunk >> 3, c8 = chunk & 7;
        int sc = c8 ^ (row & 7);
        int gr = row0 + row; if (gr >= M_) gr = M_ - 1;
        const __hip_bfloat16* src = Ax + (size_t)gr * 64 + sc * 8;
        __builtin_amdgcn_global_load_lds(
            (const void __attribute__((address_space(1)))*)src,
            (void __attribute__((address_space(3)))*)(As + chunk * 8), 16, 0, 0);
    }
    __syncthreads();

    f32x4 acc[4][2] = {};
#pragma unroll
    for (int ks = 0; ks < 2; ++ks) {
        short8v b[2];
#pragma unroll
        for (int nf = 0; nf < 2; ++nf)
            b[nf] = *(const short8v*)&Bt[(size_t)(w * 32 + nf * 16 + lr) * 64 + ks * 32 + lg * 8];
        short8v a[4];
        int kc = ks * 4 + lg;
#pragma unroll
        for (int mf = 0; mf < 4; ++mf) {
            int rl = mf * 16 + lr;
            a[mf] = *(const short8v*)&As[(rl * 8 + (kc ^ (rl & 7))) * 8];
        }
#pragma unroll
        for (int mf = 0; mf < 4; ++mf)
#pragma unroll
            for (int nf = 0; nf < 2; ++nf)
                acc[mf][nf] = __builtin_amdgcn_mfma_f32_16x16x32_bf16(
                    a[mf], b[nf], acc[mf][nf], 0, 0, 0);
    }
#pragma unroll
    for (int mf = 0; mf < 4; ++mf) {
#pragma unroll
        for (int jj = 0; jj < 4; ++jj) {
            int r = row0 + mf * 16 + lg * 4 + jj;
            if (r < M_) {
#pragma unroll
                for (int nf = 0; nf < 2; ++nf) {
                    int c = w * 32 + nf * 16 + lr;
                    float v = acc[mf][nf][jj] + bias[c];
                    h[(size_t)r * HID + c] = v;
                    hb[(size_t)r * HID + c] = __float2bfloat16(v);
                }
            }
        }
    }
}

// ---------------- bf16 MFMA GEMM: hproj[M][512] = h_bf16[M][128] @ W^T ----------------
// One block = 64 rows x all 512 cols; 4 waves, wave w = head w (64x128 tile).
// C-store via LDS staging (reuse As) -> full-row dwordx4 coalesced writes.

__global__ __launch_bounds__(256) void gemm_mfma(
    const __hip_bfloat16* __restrict__ A,   // [M][128]
    const __hip_bfloat16* __restrict__ Bt,  // [512][128]
    const float* __restrict__ att_s_l,      // [HEADS][128]
    const float* __restrict__ att_d_l,
    __hip_bfloat16* __restrict__ C,         // [M][512]
    float* __restrict__ a_s, float* __restrict__ a_d) {
    __shared__ __attribute__((aligned(16))) __hip_bfloat16 As[16 * 520];  // 16.25KB: A-tile (8192) & C-staging (8320)
    __shared__ float sRed[HEADS][2][64];
    const int M_ = N_NODES;
    const int TP = 520;                       // padded staging row (bf16 elems)
    int tid = threadIdx.x;
    int lane = tid & 63, w = tid >> 6;        // w = head
    int lr = lane & 15, lg = lane >> 4;
    int row0 = blockIdx.x * 64;

#pragma unroll
    for (int it = 0; it < 4; ++it) {
        int chunk = it * 256 + tid;
        int row = chunk >> 4, c16 = chunk & 15;
        int sc = c16 ^ (row & 15);
        const __hip_bfloat16* src = A + (size_t)(row0 + row) * 128 + sc * 8;
        __builtin_amdgcn_global_load_lds(
            (const void __attribute__((address_space(1)))*)src,
            (void __attribute__((address_space(3)))*)(As + chunk * 8), 16, 0, 0);
    }
    __syncthreads();

    f32x4 acc[4][8] = {};
#pragma unroll
    for (int ks = 0; ks < 4; ++ks) {
        short8v b[8];
#pragma unroll
        for (int nf = 0; nf < 8; ++nf)
            b[nf] = *(const short8v*)&Bt[(size_t)(w * 128 + nf * 16 + lr) * 128 + ks * 32 + lg * 8];
        short8v a[4];
        int kc = ks * 4 + lg;
#pragma unroll
        for (int mf = 0; mf < 4; ++mf) {
            int rl = mf * 16 + lr;
            a[mf] = *(const short8v*)&As[(rl * 16 + (kc ^ (rl & 15))) * 8];
        }
#pragma unroll
        for (int mf = 0; mf < 4; ++mf)
#pragma unroll
            for (int nf = 0; nf < 8; ++nf)
                acc[mf][nf] = __builtin_amdgcn_mfma_f32_16x16x32_bf16(
                    a[mf], b[nf], acc[mf][nf], 0, 0, 0);
    }

    // fused alpha: dot each output row (this head's 128 cols) with att vectors
    float asv[8], adv[8];
#pragma unroll
    for (int nf = 0; nf < 8; ++nf) {
        asv[nf] = att_s_l[w * HID + nf * 16 + lr];
        adv[nf] = att_d_l[w * HID + nf * 16 + lr];
    }
#pragma unroll
    for (int mf = 0; mf < 4; ++mf) {
#pragma unroll
        for (int j = 0; j < 4; ++j) {
            float ps = 0.f, pd = 0.f;
#pragma unroll
            for (int nf = 0; nf < 8; ++nf) {
                ps = fmaf(acc[mf][nf][j], asv[nf], ps);
                pd = fmaf(acc[mf][nf][j], adv[nf], pd);
            }
#pragma unroll
            for (int off = 1; off < 16; off <<= 1) {
                ps += __shfl_xor(ps, off);
                pd += __shfl_xor(pd, off);
            }
            if (lr == 0) {
                sRed[w][0][mf * 16 + lg * 4 + j] = ps;
                sRed[w][1][mf * 16 + lg * 4 + j] = pd;
            }
        }
    }
    __syncthreads();
    {
        int ww = tid & 3, rr = tid >> 2;
        int gr = row0 + rr;
        if (gr < M_) {
            a_s[gr * HEADS + ww] = sRed[ww][0][rr];
            a_d[gr * HEADS + ww] = sRed[ww][1][rr];
        }
    }

    // C store: per 16-row slab, stage bf16 tile in LDS then write full rows coalesced
    for (int mf = 0; mf < 4; ++mf) {
        __syncthreads();
#pragma unroll
        for (int nf = 0; nf < 8; ++nf)
#pragma unroll
            for (int j = 0; j < 4; ++j)
                As[(lg * 4 + j) * TP + w * 128 + nf * 16 + lr] =
                    __float2bfloat16(acc[mf][nf][j]);
        __syncthreads();
#pragma unroll
        for (int pass = 0; pass < 4; ++pass) {
            int r = pass * 4 + (tid >> 6);
            int grow = row0 + mf * 16 + r;
            int seg = tid & 63;
            if (grow < M_) {
                uint4 v = *(const uint4*)&As[r * TP + seg * 8];
                *(uint4*)&C[(size_t)grow * 512 + seg * 8] = v;
            }
        }
    }
}

// ---- fused per-dst-node: segment softmax + weighted bf16 gather-sum + head-mean
// ---- + bias + relu + residual + LayerNorm. One wave per node.
// ---- Phase C: lane = head(l>>4) x 16B-block(l&15); 4 outstanding dwordx4 gathers.

__global__ __launch_bounds__(256) void edge_kernel(
    const int* __restrict__ row_ptr, const int* __restrict__ colidx,
    const __hip_bfloat16* __restrict__ hproj, const float* __restrict__ a_s,
    const float* __restrict__ a_d, const float* __restrict__ conv_b,
    const float* __restrict__ ln_g, const float* __restrict__ ln_b,
    float* __restrict__ h, __hip_bfloat16* __restrict__ hb) {
    __shared__ float eLds[4][MAXD * 4];
    __shared__ int sLds[4][MAXD];
    int wv = threadIdx.x >> 6;
    int lane = threadIdx.x & 63;
    int n = blockIdx.x * 4 + wv;
    if (n >= N_NODES) return;
    int beg = row_ptr[n], end = row_ptr[n + 1];
    int deg = end - beg;

    int hh = lane >> 4;       // head owned in phase C / epilogue
    int j  = lane & 15;       // 16B channel block within head
    float acc[8] = {0.f, 0.f, 0.f, 0.f, 0.f, 0.f, 0.f, 0.f};
    float inv_own;
    const __hip_bfloat16* hbase = hproj + hh * 128 + j * 8;

    if (deg <= MAXD) {
        // phase A: logits once, edge-parallel (lane = ja*4 + ha)
        int ja = lane >> 2, ha = lane & 3;
        float adh = a_d[n * 4 + ha];
        float mx = -3.4e38f;
        for (int c = 0; c < deg; c += 16) {
            int idx = c + ja;
            float e = -3.4e38f;
            if (idx < deg) {
                int s = colidx[beg + idx];
                if (ha == 0) sLds[wv][idx] = s;
                e = a_s[s * 4 + ha] + adh;
                e = (e > 0.f) ? e : NEG_SLOPE * e;
            }
            eLds[wv][idx * 4 + ha] = e;
            mx = fmaxf(mx, e);
        }
        mx = fmaxf(mx, __shfl_xor(mx, 4));
        mx = fmaxf(mx, __shfl_xor(mx, 8));
        mx = fmaxf(mx, __shfl_xor(mx, 16));
        mx = fmaxf(mx, __shfl_xor(mx, 32));
        // phase B: exp in parallel layout, in-place p, denom
        float dsum = 0.f;
        for (int c = 0; c < deg; c += 16) {
            int idx = c + ja;
            if (idx < deg) {
                float p = __expf(eLds[wv][idx * 4 + ha] - mx);
                eLds[wv][idx * 4 + ha] = p;
                dsum += p;
            }
        }
        dsum += __shfl_xor(dsum, 4);
        dsum += __shfl_xor(dsum, 8);
        dsum += __shfl_xor(dsum, 16);
        dsum += __shfl_xor(dsum, 32);
        float dh = __shfl(dsum, hh);            // lane q<4 holds head q's denom
        inv_own = 1.f / (dh + 1e-16f);
        // phase C: 4 outstanding dwordx4 gathers per iteration
        int i = 0;
        for (; i + 3 < deg; i += 4) {
            int ss[4]; float pp[4]; uint4 uu[4];
#pragma unroll
            for (int k = 0; k < 4; ++k) {
                ss[k] = sLds[wv][i + k];
                pp[k] = eLds[wv][(i + k) * 4 + hh];
            }
#pragma unroll
            for (int k = 0; k < 4; ++k)
                uu[k] = *(const uint4*)(hbase + (size_t)ss[k] * 512);
#pragma unroll
            for (int k = 0; k < 4; ++k) {
                acc[0] = fmaf(pp[k], blo(uu[k].x), acc[0]);
                acc[1] = fmaf(pp[k], bhi(uu[k].x), acc[1]);
                acc[2] = fmaf(pp[k], blo(uu[k].y), acc[2]);
                acc[3] = fmaf(pp[k], bhi(uu[k].y), acc[3]);
                acc[4] = fmaf(pp[k], blo(uu[k].z), acc[4]);
                acc[5] = fmaf(pp[k], bhi(uu[k].z), acc[5]);
                acc[6] = fmaf(pp[k], blo(uu[k].w), acc[6]);
                acc[7] = fmaf(pp[k], bhi(uu[k].w), acc[7]);
            }
        }
        for (; i < deg; ++i) {
            int s0 = sLds[wv][i];
            float p0 = eLds[wv][i * 4 + hh];
            uint4 u0 = *(const uint4*)(hbase + (size_t)s0 * 512);
            acc[0] = fmaf(p0, blo(u0.x), acc[0]);
            acc[1] = fmaf(p0, bhi(u0.x), acc[1]);
            acc[2] = fmaf(p0, blo(u0.y), acc[2]);
            acc[3] = fmaf(p0, bhi(u0.y), acc[3]);
            acc[4] = fmaf(p0, blo(u0.z), acc[4]);
            acc[5] = fmaf(p0, bhi(u0.z), acc[5]);
            acc[6] = fmaf(p0, blo(u0.w), acc[6]);
            acc[7] = fmaf(p0, bhi(u0.w), acc[7]);
        }
    } else {
        // fallback (statistically never): own-head two-pass
        float adh = a_d[n * 4 + hh];
        float m = -3.4e38f;
        for (int i = beg + j; i < end; i += 16) {
            int s = colidx[i];
            float e = a_s[s * 4 + hh] + adh;
            e = (e > 0.f) ? e : NEG_SLOPE * e;
            m = fmaxf(m, e);
        }
        m = fmaxf(m, __shfl_xor(m, 1));
        m = fmaxf(m, __shfl_xor(m, 2));
        m = fmaxf(m, __shfl_xor(m, 4));
        m = fmaxf(m, __shfl_xor(m, 8));
        float denom = 0.f;
        for (int i = beg; i < end; ++i) {
            int s = colidx[i];
            float e = a_s[s * 4 + hh] + adh;
            e = (e > 0.f) ? e : NEG_SLOPE * e;
            float p = __expf(e - m);
            denom += p;
            uint4 u0 = *(const uint4*)(hbase + (size_t)s * 512);
            acc[0] = fmaf(p, blo(u0.x), acc[0]);
            acc[1] = fmaf(p, bhi(u0.x), acc[1]);
            acc[2] = fmaf(p, blo(u0.y), acc[2]);
            acc[3] = fmaf(p, bhi(u0.y), acc[3]);
            acc[4] = fmaf(p, blo(u0.z), acc[4]);
            acc[5] = fmaf(p, bhi(u0.z), acc[5]);
            acc[6] = fmaf(p, blo(u0.w), acc[6]);
            acc[7] = fmaf(p, bhi(u0.w), acc[7]);
        }
        inv_own = 1.f / (denom + 1e-16f);
    }

    // epilogue: r[k] = per-head result; sum heads via xor 16,32; then bias+relu+res+LN
    float r[8];
#pragma unroll
    for (int k = 0; k < 8; ++k) r[k] = acc[k] * inv_own;
#pragma unroll
    for (int k = 0; k < 8; ++k) {
        r[k] += __shfl_xor(r[k], 16);
        r[k] += __shfl_xor(r[k], 32);
    }
    int c0 = j * 8;
    float4 cb0 = *(const float4*)&conv_b[c0];
    float4 cb1 = *(const float4*)&conv_b[c0 + 4];
    float4 h0 = *(const float4*)&h[(size_t)n * HID + c0];
    float4 h1 = *(const float4*)&h[(size_t)n * HID + c0 + 4];
    float cb[8] = {cb0.x, cb0.y, cb0.z, cb0.w, cb1.x, cb1.y, cb1.z, cb1.w};
    float hr[8] = {h0.x, h0.y, h0.z, h0.w, h1.x, h1.y, h1.z, h1.w};
#pragma unroll
    for (int k = 0; k < 8; ++k) {
        r[k] = fmaxf(0.25f * r[k] + cb[k], 0.f) + hr[k];
    }
    float s1 = 0.f;
#pragma unroll
    for (int k = 0; k < 8; ++k) s1 += r[k];
#pragma unroll
    for (int off = 1; off < 64; off <<= 1) s1 += __shfl_xor(s1, off);
    float mu = s1 * (1.f / (4.f * HID));       // 4x redundancy across head groups
    float s2 = 0.f;
#pragma unroll
    for (int k = 0; k < 8; ++k) {
        r[k] -= mu;
        s2 += r[k] * r[k];
    }
#pragma unroll
    for (int off = 1; off < 64; off <<= 1) s2 += __shfl_xor(s2, off);
    float rstd = rsqrtf(s2 * (1.f / (4.f * HID)) + LN_EPS);
    float4 g0 = *(const float4*)&ln_g[c0];
    float4 g1 = *(const float4*)&ln_g[c0 + 4];
    float4 b0 = *(const float4*)&ln_b[c0];
    float4 b1 = *(const float4*)&ln_b[c0 + 4];
    float gg[8] = {g0.x, g0.y, g0.z, g0.w, g1.x, g1.y, g1.z, g1.w};
    float bb[8] = {b0.x, b0.y, b0.z, b0.w, b1.x, b1.y, b1.z, b1.w};
    float o[8];
#pragma unroll
    for (int k = 0; k < 8; ++k) o[k] = r[k] * rstd * gg[k] + bb[k];
    if (hh == 0) {
        *(float4*)&h[(size_t)n * HID + c0] = make_float4(o[0], o[1], o[2], o[3]);
        *(float4*)&h[(size_t)n * HID + c0 + 4] = make_float4(o[4], o[5], o[6], o[7]);
        __hip_bfloat162 q[4];
#pragma unroll
        for (int k = 0; k < 4; ++k) {
            q[k].x = __float2bfloat16(o[2 * k]);
            q[k].y = __float2bfloat16(o[2 * k + 1]);
        }
        *(uint4*)&hb[(size_t)n * HID + c0] = *(uint4*)q;
    }
}

// ---------------- global mean pool (batch is sorted) ----------------

__global__ __launch_bounds__(128) void pool_kernel(
    const float* __restrict__ h, const int* __restrict__ batch,
    float* __restrict__ pool_sum, int* __restrict__ pool_cnt) {
    int base = blockIdx.x * 64;
    int c = threadIdx.x;
    float acc = 0.f; int cur = -1;
    for (int i = 0; i < 64; ++i) {
        int n = base + i;
        if (n >= N_NODES) break;
        int g = batch[n];
        if (g != cur) {
            if (cur >= 0) atomicAdd(&pool_sum[cur * HID + c], acc);
            acc = 0.f; cur = g;
        }
        acc += h[(size_t)n * HID + c];
    }
    if (cur >= 0) atomicAdd(&pool_sum[cur * HID + c], acc);
    if (c == 0) {
        int run = 0; int curg = -1;
        for (int i = 0; i < 64; ++i) {
            int n = base + i;
            if (n >= N_NODES) break;
            int g = batch[n];
            if (g != curg) {
                if (curg >= 0) atomicAdd(&pool_cnt[curg], run);
                curg = g; run = 0;
            }
            run++;
        }
        if (curg >= 0) atomicAdd(&pool_cnt[curg], run);
    }
}

__global__ void finalize_kernel(const float* __restrict__ pool_sum,
                                const int* __restrict__ pool_cnt,
                                float* __restrict__ out) {
    int i = blockIdx.x * blockDim.x + threadIdx.x;
    if (i >= GRAPHS * HID) return;
    int g = i / HID;
    int c = pool_cnt[g];
    float cnt = (float)(c > 0 ? c : 1);
    out[i] = pool_sum[i] / cnt;
}

// ---------------- host ----------------

extern "C" void kernel_launch(void* const* d_in, const int* in_sizes, int n_in,
                              void* d_out, int out_size, void* d_ws, size_t ws_size,
                              hipStream_t stream) {
    const float* x      = (const float*)d_in[0];
    const int*   ei     = (const int*)d_in[1];
    const int*   batch  = (const int*)d_in[2];
    const float* W_in   = (const float*)d_in[3];
    const float* b_in   = (const float*)d_in[4];
    const float* Ws     = (const float*)d_in[5];
    const float* att_src= (const float*)d_in[6];
    const float* att_dst= (const float*)d_in[7];
    const float* conv_b = (const float*)d_in[8];
    const float* ln_g   = (const float*)d_in[9];
    const float* ln_b   = (const float*)d_in[10];
    float* out = (float*)d_out;

    char* ws = (char*)d_ws;
    size_t off = 0;
    auto alloc = [&](size_t bytes) -> void* {
        void* p = ws + off;
        off = (off + bytes + 255) & ~(size_t)255;
        return p;
    };
    float* h            = (float*)alloc((size_t)N_NODES * HID * 4);
    __hip_bfloat16* hb  = (__hip_bfloat16*)alloc((size_t)N_NODES * HID * 2);
    __hip_bfloat16* hpj = (__hip_bfloat16*)alloc((size_t)N_NODES * HEADS * HID * 2);
    __hip_bfloat16* Wt  = (__hip_bfloat16*)alloc((size_t)LAYERS * 512 * 128 * 2);
    __hip_bfloat16* Wti = (__hip_bfloat16*)alloc((size_t)HID * IN_DIM * 2);
    __hip_bfloat16* xb  = (__hip_bfloat16*)alloc((size_t)N_NODES * IN_DIM * 2);
    float* a_s    = (float*)alloc((size_t)N_NODES * HEADS * 4);
    float* a_d    = (float*)alloc((size_t)N_NODES * HEADS * 4);
    int* row_ptr  = (int*)alloc((N_NODES + 1) * 4);
    int* cursor   = (int*)alloc(N_NODES * 4);
    int* colidx   = (int*)alloc((size_t)TOT_E * 4);
    int* counts   = (int*)alloc(N_NODES * 4);
    float* pool   = (float*)alloc(GRAPHS * HID * 4);
    int* cnt      = (int*)alloc(GRAPHS * 4);

    zero_kernel<<<(N_NODES + GRAPHS * HID + GRAPHS + 255) / 256, 256, 0, stream>>>(
        counts, pool, cnt);
    count_kernel<<<(TOT_E + 255) / 256, 256, 0, stream>>>(ei, counts);
    scan_kernel<<<1, 1024, 0, stream>>>(counts, row_ptr, cursor);
    fill_kernel<<<(TOT_E + 255) / 256, 256, 0, stream>>>(ei, cursor, colidx);
    pack_all<<<(NW + NWIN + NX + 255) / 256, 256, 0, stream>>>(Ws, W_in, x, Wt, Wti, xb);

    gemm_in<<<(N_NODES + 63) / 64, 256, 0, stream>>>(xb, Wti, b_in, h, hb);

    for (int l = 0; l < LAYERS; ++l) {
        gemm_mfma<<<(N_NODES + 63) / 64, 256, 0, stream>>>(
            hb, Wt + (size_t)l * 512 * 128,
            att_src + (size_t)l * HEADS * HID, att_dst + (size_t)l * HEADS * HID,
            hpj, a_s, a_d);
        edge_kernel<<<(N_NODES + 3) / 4, 256, 0, stream>>>(
            row_ptr, colidx, hpj, a_s, a_d,
            conv_b + (size_t)l * HID, ln_g + (size_t)l * HID, ln_b + (size_t)l * HID,
            h, hb);
    }

    pool_kernel<<<(N_NODES + 63) / 64, 128, 0, stream>>>(h, batch, pool, cnt);
    finalize_kernel<<<(GRAPHS * HID + 255) / 256, 256, 0, stream>>>(pool, cnt, out);
}

// Round 6
// 297.958 us; speedup vs baseline: 2.0376x; 1.1189x over previous
//
#include <hip/hip_runtime.h>
#include <hip/hip_bf16.h>
#include <math.h>

#define N_NODES 20000
#define N_EDGES 320000
#define IN_DIM 64
#define HID 128
#define HEADS 4
#define LAYERS 3
#define GRAPHS 64
#define TOT_E (N_EDGES + N_NODES)
#define NEG_SLOPE 0.2f
#define LN_EPS 1e-5f
#define MAXD 96   // fast-path max degree; fallback below

typedef __attribute__((ext_vector_type(8))) short short8v;
typedef __attribute__((ext_vector_type(4))) float f32x4;
typedef __attribute__((ext_vector_type(2))) float f32x2;

__device__ __forceinline__ float blo(unsigned int u) { return __uint_as_float(u << 16); }
__device__ __forceinline__ float bhi(unsigned int u) { return __uint_as_float(u & 0xffff0000u); }

// ---------------- CSR build (by dst), rebuilt deterministically every call ----------------

__global__ void count_kernel(const int* __restrict__ ei, int* __restrict__ counts) {
    int e = blockIdx.x * blockDim.x + threadIdx.x;
    if (e >= TOT_E) return;
    int dst = (e < N_EDGES) ? ei[N_EDGES + e] : (e - N_EDGES);
    atomicAdd(&counts[dst], 1);
}

__global__ void scan_kernel(const int* __restrict__ counts, int* __restrict__ row_ptr,
                            int* __restrict__ cursor) {
    __shared__ int part[1024];
    int tid = threadIdx.x;
    const int per = (N_NODES + 1023) / 1024;  // 20
    int start = tid * per;
    int end = start + per; if (end > N_NODES) end = N_NODES;
    int s = 0;
    if (end == start + 20) {
        const int4* c4 = (const int4*)(counts + start);
#pragma unroll
        for (int q = 0; q < 5; ++q) {
            int4 v = c4[q];
            s += v.x + v.y + v.z + v.w;
        }
    } else {
        for (int i = start; i < end; ++i) s += counts[i];
    }
    part[tid] = s;
    __syncthreads();
    for (int off = 1; off < 1024; off <<= 1) {
        int v = (tid >= off) ? part[tid - off] : 0;
        __syncthreads();
        part[tid] += v;
        __syncthreads();
    }
    int run = (tid > 0) ? part[tid - 1] : 0;
    for (int i = start; i < end; ++i) {
        row_ptr[i] = run; cursor[i] = run; run += counts[i];
    }
    if (tid == 1023) row_ptr[N_NODES] = part[1023];
}

__global__ void fill_kernel(const int* __restrict__ ei, int* __restrict__ cursor,
                            int* __restrict__ colidx) {
    int e = blockIdx.x * blockDim.x + threadIdx.x;
    if (e >= TOT_E) return;
    int src, dst;
    if (e < N_EDGES) { src = ei[e]; dst = ei[N_EDGES + e]; }
    else { src = e - N_EDGES; dst = src; }
    int pos = atomicAdd(&cursor[dst], 1);
    colidx[pos] = src;
}

__global__ void zero_kernel(int* __restrict__ counts) {
    int i = blockIdx.x * blockDim.x + threadIdx.x;
    if (i < N_NODES) counts[i] = 0;
}

// ------------- pack: Ws->Wt (transposed bf16), W_in->Wt_in (transposed bf16), x->xb -------------

#define NW (LAYERS * 512 * 128)
#define NWIN (HID * IN_DIM)
#define NX (N_NODES * IN_DIM)

__global__ void pack_all(const float* __restrict__ Ws, const float* __restrict__ W_in,
                         const float* __restrict__ x, __hip_bfloat16* __restrict__ Wt,
                         __hip_bfloat16* __restrict__ Wt_in, __hip_bfloat16* __restrict__ xb) {
    int i = blockIdx.x * blockDim.x + threadIdx.x;
    if (i < NW) {
        int l = i / (512 * 128);
        int r = i % (512 * 128);
        int n = r / 128, k = r % 128;
        Wt[i] = __float2bfloat16(Ws[(size_t)l * 128 * 512 + k * 512 + n]);
    } else if (i < NW + NWIN) {
        int r = i - NW;                 // Wt_in[n][k], n<128, k<64
        int n = r / 64, k = r % 64;
        Wt_in[r] = __float2bfloat16(W_in[k * 128 + n]);
    } else if (i < NW + NWIN + NX) {
        int r = i - NW - NWIN;
        xb[r] = __float2bfloat16(x[r]);
    }
}

// ---------------- input layer MFMA: h[M][128] = xb[M][64] @ W_in + b_in ----------------

__global__ __launch_bounds__(256) void gemm_in(
    const __hip_bfloat16* __restrict__ Ax,   // [M][64]
    const __hip_bfloat16* __restrict__ Bt,   // [128][64]
    const float* __restrict__ bias,          // [128]
    float* __restrict__ h, __hip_bfloat16* __restrict__ hb) {
    __shared__ __hip_bfloat16 As[64 * 64];    // 8KB, swizzled 16B chunks
    const int M_ = N_NODES;
    int tid = threadIdx.x;
    int lane = tid & 63, w = tid >> 6;
    int lr = lane & 15, lg = lane >> 4;
    int row0 = blockIdx.x * 64;
#pragma unroll
    for (int it = 0; it < 2; ++it) {
        int chunk = it * 256 + tid;
        int row = chunk >> 3, c8 = chunk & 7;
        int sc = c8 ^ (row & 7);
        int gr = row0 + row; if (gr >= M_) gr = M_ - 1;
        const __hip_bfloat16* src = Ax + (size_t)gr * 64 + sc * 8;
        __builtin_amdgcn_global_load_lds(
            (const void __attribute__((address_space(1)))*)src,
            (void __attribute__((address_space(3)))*)(As + chunk * 8), 16, 0, 0);
    }
    __syncthreads();

    f32x4 acc[4][2] = {};
#pragma unroll
    for (int ks = 0; ks < 2; ++ks) {
        short8v b[2];
#pragma unroll
        for (int nf = 0; nf < 2; ++nf)
            b[nf] = *(const short8v*)&Bt[(size_t)(w * 32 + nf * 16 + lr) * 64 + ks * 32 + lg * 8];
        short8v a[4];
        int kc = ks * 4 + lg;
#pragma unroll
        for (int mf = 0; mf < 4; ++mf) {
            int rl = mf * 16 + lr;
            a[mf] = *(const short8v*)&As[(rl * 8 + (kc ^ (rl & 7))) * 8];
        }
#pragma unroll
        for (int mf = 0; mf < 4; ++mf)
#pragma unroll
            for (int nf = 0; nf < 2; ++nf)
                acc[mf][nf] = __builtin_amdgcn_mfma_f32_16x16x32_bf16(
                    a[mf], b[nf], acc[mf][nf], 0, 0, 0);
    }
#pragma unroll
    for (int mf = 0; mf < 4; ++mf) {
#pragma unroll
        for (int jj = 0; jj < 4; ++jj) {
            int r = row0 + mf * 16 + lg * 4 + jj;
            if (r < M_) {
#pragma unroll
                for (int nf = 0; nf < 2; ++nf) {
                    int c = w * 32 + nf * 16 + lr;
                    float v = acc[mf][nf][jj] + bias[c];
                    h[(size_t)r * HID + c] = v;
                    hb[(size_t)r * HID + c] = __float2bfloat16(v);
                }
            }
        }
    }
}

// ---------------- bf16 MFMA GEMM: hproj8[M][512] (fp8) = h_bf16[M][128] @ W^T ----------------
// One block = 64 rows x all 512 cols; 4 waves, wave w = head w (64x128 tile).
// C-store: stage bf16 slab in LDS -> convert to fp8 e4m3 -> coalesced 512B rows.

__global__ __launch_bounds__(256) void gemm_mfma(
    const __hip_bfloat16* __restrict__ A,   // [M][128]
    const __hip_bfloat16* __restrict__ Bt,  // [512][128]
    const float* __restrict__ att_s_l,      // [HEADS][128]
    const float* __restrict__ att_d_l,
    unsigned char* __restrict__ C8,         // [M][512] fp8
    float* __restrict__ a_s, float* __restrict__ a_d) {
    __shared__ __attribute__((aligned(16))) __hip_bfloat16 As[16 * 520];
    __shared__ float sRed[HEADS][2][64];
    const int M_ = N_NODES;
    const int TP = 520;
    int tid = threadIdx.x;
    int lane = tid & 63, w = tid >> 6;        // w = head
    int lr = lane & 15, lg = lane >> 4;
    int row0 = blockIdx.x * 64;

#pragma unroll
    for (int it = 0; it < 4; ++it) {
        int chunk = it * 256 + tid;
        int row = chunk >> 4, c16 = chunk & 15;
        int sc = c16 ^ (row & 15);
        const __hip_bfloat16* src = A + (size_t)(row0 + row) * 128 + sc * 8;
        __builtin_amdgcn_global_load_lds(
            (const void __attribute__((address_space(1)))*)src,
            (void __attribute__((address_space(3)))*)(As + chunk * 8), 16, 0, 0);
    }
    __syncthreads();

    f32x4 acc[4][8] = {};
#pragma unroll
    for (int ks = 0; ks < 4; ++ks) {
        short8v b[8];
#pragma unroll
        for (int nf = 0; nf < 8; ++nf)
            b[nf] = *(const short8v*)&Bt[(size_t)(w * 128 + nf * 16 + lr) * 128 + ks * 32 + lg * 8];
        short8v a[4];
        int kc = ks * 4 + lg;
#pragma unroll
        for (int mf = 0; mf < 4; ++mf) {
            int rl = mf * 16 + lr;
            a[mf] = *(const short8v*)&As[(rl * 16 + (kc ^ (rl & 15))) * 8];
        }
#pragma unroll
        for (int mf = 0; mf < 4; ++mf)
#pragma unroll
            for (int nf = 0; nf < 8; ++nf)
                acc[mf][nf] = __builtin_amdgcn_mfma_f32_16x16x32_bf16(
                    a[mf], b[nf], acc[mf][nf], 0, 0, 0);
    }

    // fused alpha: dot each output row (this head's 128 cols) with att vectors
    float asv[8], adv[8];
#pragma unroll
    for (int nf = 0; nf < 8; ++nf) {
        asv[nf] = att_s_l[w * HID + nf * 16 + lr];
        adv[nf] = att_d_l[w * HID + nf * 16 + lr];
    }
#pragma unroll
    for (int mf = 0; mf < 4; ++mf) {
#pragma unroll
        for (int j = 0; j < 4; ++j) {
            float ps = 0.f, pd = 0.f;
#pragma unroll
            for (int nf = 0; nf < 8; ++nf) {
                ps = fmaf(acc[mf][nf][j], asv[nf], ps);
                pd = fmaf(acc[mf][nf][j], adv[nf], pd);
            }
#pragma unroll
            for (int off = 1; off < 16; off <<= 1) {
                ps += __shfl_xor(ps, off);
                pd += __shfl_xor(pd, off);
            }
            if (lr == 0) {
                sRed[w][0][mf * 16 + lg * 4 + j] = ps;
                sRed[w][1][mf * 16 + lg * 4 + j] = pd;
            }
        }
    }
    __syncthreads();
    {
        int ww = tid & 3, rr = tid >> 2;
        int gr = row0 + rr;
        if (gr < M_) {
            a_s[gr * HEADS + ww] = sRed[ww][0][rr];
            a_d[gr * HEADS + ww] = sRed[ww][1][rr];
        }
    }

    // C store: per 16-row slab, stage bf16 in LDS, convert to fp8, coalesced 512B rows
    for (int mf = 0; mf < 4; ++mf) {
        __syncthreads();
#pragma unroll
        for (int nf = 0; nf < 8; ++nf)
#pragma unroll
            for (int j = 0; j < 4; ++j)
                As[(lg * 4 + j) * TP + w * 128 + nf * 16 + lr] =
                    __float2bfloat16(acc[mf][nf][j]);
        __syncthreads();
#pragma unroll
        for (int pass = 0; pass < 4; ++pass) {
            int r = pass * 4 + (tid >> 6);
            int grow = row0 + mf * 16 + r;
            int seg = tid & 63;
            if (grow < M_) {
                uint4 v = *(const uint4*)&As[r * TP + seg * 8];
                float f0 = blo(v.x), f1 = bhi(v.x), f2 = blo(v.y), f3 = bhi(v.y);
                float f4 = blo(v.z), f5 = bhi(v.z), f6 = blo(v.w), f7 = bhi(v.w);
                int d0 = 0, d1 = 0;
                d0 = __builtin_amdgcn_cvt_pk_fp8_f32(f0, f1, d0, false);
                d0 = __builtin_amdgcn_cvt_pk_fp8_f32(f2, f3, d0, true);
                d1 = __builtin_amdgcn_cvt_pk_fp8_f32(f4, f5, d1, false);
                d1 = __builtin_amdgcn_cvt_pk_fp8_f32(f6, f7, d1, true);
                *(uint2*)&C8[(size_t)grow * 512 + seg * 8] = make_uint2((unsigned)d0, (unsigned)d1);
            }
        }
    }
}

// ---- fused per-dst-node: segment softmax + weighted fp8 gather-sum + head-mean
// ---- + bias + relu + residual + LayerNorm. One wave per node.
// ---- Phase C: lane = head(l>>4) x 8B-block(l&15); one uint2 (8 fp8) per edge per lane.

__global__ __launch_bounds__(256) void edge_kernel(
    const int* __restrict__ row_ptr, const int* __restrict__ colidx,
    const unsigned char* __restrict__ hproj8, const float* __restrict__ a_s,
    const float* __restrict__ a_d, const float* __restrict__ conv_b,
    const float* __restrict__ ln_g, const float* __restrict__ ln_b,
    float* __restrict__ h, __hip_bfloat16* __restrict__ hb) {
    __shared__ float eLds[4][MAXD * 4];
    __shared__ int sLds[4][MAXD];
    int wv = threadIdx.x >> 6;
    int lane = threadIdx.x & 63;
    int n = blockIdx.x * 4 + wv;
    if (n >= N_NODES) return;
    int beg = row_ptr[n], end = row_ptr[n + 1];
    int deg = end - beg;

    int hh = lane >> 4;       // head owned in phase C / epilogue
    int j  = lane & 15;       // 8-channel block within head
    float acc[8] = {0.f, 0.f, 0.f, 0.f, 0.f, 0.f, 0.f, 0.f};
    float inv_own;
    const unsigned char* hbase = hproj8 + hh * 128 + j * 8;

    if (deg <= MAXD) {
        // phase A: logits once, edge-parallel (lane = ja*4 + ha)
        int ja = lane >> 2, ha = lane & 3;
        float adh = a_d[n * 4 + ha];
        float mx = -3.4e38f;
        for (int c = 0; c < deg; c += 16) {
            int idx = c + ja;
            float e = -3.4e38f;
            if (idx < deg) {
                int s = colidx[beg + idx];
                if (ha == 0) sLds[wv][idx] = s;
                e = a_s[s * 4 + ha] + adh;
                e = (e > 0.f) ? e : NEG_SLOPE * e;
            }
            eLds[wv][idx * 4 + ha] = e;
            mx = fmaxf(mx, e);
        }
        mx = fmaxf(mx, __shfl_xor(mx, 4));
        mx = fmaxf(mx, __shfl_xor(mx, 8));
        mx = fmaxf(mx, __shfl_xor(mx, 16));
        mx = fmaxf(mx, __shfl_xor(mx, 32));
        // phase B: exp in parallel layout, in-place p, denom
        float dsum = 0.f;
        for (int c = 0; c < deg; c += 16) {
            int idx = c + ja;
            if (idx < deg) {
                float p = __expf(eLds[wv][idx * 4 + ha] - mx);
                eLds[wv][idx * 4 + ha] = p;
                dsum += p;
            }
        }
        dsum += __shfl_xor(dsum, 4);
        dsum += __shfl_xor(dsum, 8);
        dsum += __shfl_xor(dsum, 16);
        dsum += __shfl_xor(dsum, 32);
        float dh = __shfl(dsum, hh);            // lane q<4 holds head q's denom
        inv_own = 1.f / (dh + 1e-16f);
        // phase C: 4 outstanding uint2 fp8 gathers per iteration
        int i = 0;
        for (; i + 3 < deg; i += 4) {
            int ss[4]; float pp[4]; uint2 uu[4];
#pragma unroll
            for (int k = 0; k < 4; ++k) {
                ss[k] = sLds[wv][i + k];
                pp[k] = eLds[wv][(i + k) * 4 + hh];
            }
#pragma unroll
            for (int k = 0; k < 4; ++k)
                uu[k] = *(const uint2*)(hbase + (size_t)ss[k] * 512);
#pragma unroll
            for (int k = 0; k < 4; ++k) {
                f32x2 a01 = __builtin_amdgcn_cvt_pk_f32_fp8(uu[k].x, false);
                f32x2 a23 = __builtin_amdgcn_cvt_pk_f32_fp8(uu[k].x, true);
                f32x2 a45 = __builtin_amdgcn_cvt_pk_f32_fp8(uu[k].y, false);
                f32x2 a67 = __builtin_amdgcn_cvt_pk_f32_fp8(uu[k].y, true);
                acc[0] = fmaf(pp[k], a01[0], acc[0]);
                acc[1] = fmaf(pp[k], a01[1], acc[1]);
                acc[2] = fmaf(pp[k], a23[0], acc[2]);
                acc[3] = fmaf(pp[k], a23[1], acc[3]);
                acc[4] = fmaf(pp[k], a45[0], acc[4]);
                acc[5] = fmaf(pp[k], a45[1], acc[5]);
                acc[6] = fmaf(pp[k], a67[0], acc[6]);
                acc[7] = fmaf(pp[k], a67[1], acc[7]);
            }
        }
        for (; i < deg; ++i) {
            int s0 = sLds[wv][i];
            float p0 = eLds[wv][i * 4 + hh];
            uint2 u0 = *(const uint2*)(hbase + (size_t)s0 * 512);
            f32x2 a01 = __builtin_amdgcn_cvt_pk_f32_fp8(u0.x, false);
            f32x2 a23 = __builtin_amdgcn_cvt_pk_f32_fp8(u0.x, true);
            f32x2 a45 = __builtin_amdgcn_cvt_pk_f32_fp8(u0.y, false);
            f32x2 a67 = __builtin_amdgcn_cvt_pk_f32_fp8(u0.y, true);
            acc[0] = fmaf(p0, a01[0], acc[0]);
            acc[1] = fmaf(p0, a01[1], acc[1]);
            acc[2] = fmaf(p0, a23[0], acc[2]);
            acc[3] = fmaf(p0, a23[1], acc[3]);
            acc[4] = fmaf(p0, a45[0], acc[4]);
            acc[5] = fmaf(p0, a45[1], acc[5]);
            acc[6] = fmaf(p0, a67[0], acc[6]);
            acc[7] = fmaf(p0, a67[1], acc[7]);
        }
    } else {
        // fallback (statistically never): own-head two-pass
        float adh = a_d[n * 4 + hh];
        float m = -3.4e38f;
        for (int i = beg + j; i < end; i += 16) {
            int s = colidx[i];
            float e = a_s[s * 4 + hh] + adh;
            e = (e > 0.f) ? e : NEG_SLOPE * e;
            m = fmaxf(m, e);
        }
        m = fmaxf(m, __shfl_xor(m, 1));
        m = fmaxf(m, __shfl_xor(m, 2));
        m = fmaxf(m, __shfl_xor(m, 4));
        m = fmaxf(m, __shfl_xor(m, 8));
        float denom = 0.f;
        for (int i = beg; i < end; ++i) {
            int s = colidx[i];
            float e = a_s[s * 4 + hh] + adh;
            e = (e > 0.f) ? e : NEG_SLOPE * e;
            float p = __expf(e - m);
            denom += p;
            uint2 u0 = *(const uint2*)(hbase + (size_t)s * 512);
            f32x2 a01 = __builtin_amdgcn_cvt_pk_f32_fp8(u0.x, false);
            f32x2 a23 = __builtin_amdgcn_cvt_pk_f32_fp8(u0.x, true);
            f32x2 a45 = __builtin_amdgcn_cvt_pk_f32_fp8(u0.y, false);
            f32x2 a67 = __builtin_amdgcn_cvt_pk_f32_fp8(u0.y, true);
            acc[0] = fmaf(p, a01[0], acc[0]);
            acc[1] = fmaf(p, a01[1], acc[1]);
            acc[2] = fmaf(p, a23[0], acc[2]);
            acc[3] = fmaf(p, a23[1], acc[3]);
            acc[4] = fmaf(p, a45[0], acc[4]);
            acc[5] = fmaf(p, a45[1], acc[5]);
            acc[6] = fmaf(p, a67[0], acc[6]);
            acc[7] = fmaf(p, a67[1], acc[7]);
        }
        inv_own = 1.f / (denom + 1e-16f);
    }

    // epilogue: r[k] = per-head result; sum heads via xor 16,32; then bias+relu+res+LN
    float r[8];
#pragma unroll
    for (int k = 0; k < 8; ++k) r[k] = acc[k] * inv_own;
#pragma unroll
    for (int k = 0; k < 8; ++k) {
        r[k] += __shfl_xor(r[k], 16);
        r[k] += __shfl_xor(r[k], 32);
    }
    int c0 = j * 8;
    float4 cb0 = *(const float4*)&conv_b[c0];
    float4 cb1 = *(const float4*)&conv_b[c0 + 4];
    float4 h0 = *(const float4*)&h[(size_t)n * HID + c0];
    float4 h1 = *(const float4*)&h[(size_t)n * HID + c0 + 4];
    float cb[8] = {cb0.x, cb0.y, cb0.z, cb0.w, cb1.x, cb1.y, cb1.z, cb1.w};
    float hr[8] = {h0.x, h0.y, h0.z, h0.w, h1.x, h1.y, h1.z, h1.w};
#pragma unroll
    for (int k = 0; k < 8; ++k) {
        r[k] = fmaxf(0.25f * r[k] + cb[k], 0.f) + hr[k];
    }
    float s1 = 0.f;
#pragma unroll
    for (int k = 0; k < 8; ++k) s1 += r[k];
#pragma unroll
    for (int off = 1; off < 64; off <<= 1) s1 += __shfl_xor(s1, off);
    float mu = s1 * (1.f / (4.f * HID));       // 4x redundancy across head groups
    float s2 = 0.f;
#pragma unroll
    for (int k = 0; k < 8; ++k) {
        r[k] -= mu;
        s2 += r[k] * r[k];
    }
#pragma unroll
    for (int off = 1; off < 64; off <<= 1) s2 += __shfl_xor(s2, off);
    float rstd = rsqrtf(s2 * (1.f / (4.f * HID)) + LN_EPS);
    float4 g0 = *(const float4*)&ln_g[c0];
    float4 g1 = *(const float4*)&ln_g[c0 + 4];
    float4 b0 = *(const float4*)&ln_b[c0];
    float4 b1 = *(const float4*)&ln_b[c0 + 4];
    float gg[8] = {g0.x, g0.y, g0.z, g0.w, g1.x, g1.y, g1.z, g1.w};
    float bb[8] = {b0.x, b0.y, b0.z, b0.w, b1.x, b1.y, b1.z, b1.w};
    float o[8];
#pragma unroll
    for (int k = 0; k < 8; ++k) o[k] = r[k] * rstd * gg[k] + bb[k];
    if (hh == 0) {
        *(float4*)&h[(size_t)n * HID + c0] = make_float4(o[0], o[1], o[2], o[3]);
        *(float4*)&h[(size_t)n * HID + c0 + 4] = make_float4(o[4], o[5], o[6], o[7]);
        __hip_bfloat162 q[4];
#pragma unroll
        for (int k = 0; k < 4; ++k) {
            q[k].x = __float2bfloat16(o[2 * k]);
            q[k].y = __float2bfloat16(o[2 * k + 1]);
        }
        *(uint4*)&hb[(size_t)n * HID + c0] = *(uint4*)q;
    }
}

// ---------------- global mean pool: one block per graph (batch sorted) ----------------

__global__ __launch_bounds__(128) void pool2_kernel(
    const float* __restrict__ h, const int* __restrict__ batch,
    float* __restrict__ out) {
    int g = blockIdx.x;
    int c = threadIdx.x;
    __shared__ int sLo, sHi;
    if (c == 0) {
        int lo = 0, hi = N_NODES;
        while (lo < hi) { int m = (lo + hi) >> 1; if (batch[m] < g) lo = m + 1; else hi = m; }
        sLo = lo;
        hi = N_NODES;
        while (lo < hi) { int m = (lo + hi) >> 1; if (batch[m] < g + 1) lo = m + 1; else hi = m; }
        sHi = lo;
    }
    __syncthreads();
    int lo = sLo, hi = sHi;
    float s0 = 0.f, s1 = 0.f, s2 = 0.f, s3 = 0.f;
    int n = lo;
    for (; n + 3 < hi; n += 4) {
        s0 += h[(size_t)n * HID + c];
        s1 += h[(size_t)(n + 1) * HID + c];
        s2 += h[(size_t)(n + 2) * HID + c];
        s3 += h[(size_t)(n + 3) * HID + c];
    }
    for (; n < hi; ++n) s0 += h[(size_t)n * HID + c];
    float s = (s0 + s1) + (s2 + s3);
    int cnt = hi - lo; if (cnt < 1) cnt = 1;
    out[g * HID + c] = s / (float)cnt;
}

// ---------------- host ----------------

extern "C" void kernel_launch(void* const* d_in, const int* in_sizes, int n_in,
                              void* d_out, int out_size, void* d_ws, size_t ws_size,
                              hipStream_t stream) {
    const float* x      = (const float*)d_in[0];
    const int*   ei     = (const int*)d_in[1];
    const int*   batch  = (const int*)d_in[2];
    const float* W_in   = (const float*)d_in[3];
    const float* b_in   = (const float*)d_in[4];
    const float* Ws     = (const float*)d_in[5];
    const float* att_src= (const float*)d_in[6];
    const float* att_dst= (const float*)d_in[7];
    const float* conv_b = (const float*)d_in[8];
    const float* ln_g   = (const float*)d_in[9];
    const float* ln_b   = (const float*)d_in[10];
    float* out = (float*)d_out;

    char* ws = (char*)d_ws;
    size_t off = 0;
    auto alloc = [&](size_t bytes) -> void* {
        void* p = ws + off;
        off = (off + bytes + 255) & ~(size_t)255;
        return p;
    };
    float* h            = (float*)alloc((size_t)N_NODES * HID * 4);
    __hip_bfloat16* hb  = (__hip_bfloat16*)alloc((size_t)N_NODES * HID * 2);
    unsigned char* hpj  = (unsigned char*)alloc((size_t)N_NODES * HEADS * HID);
    __hip_bfloat16* Wt  = (__hip_bfloat16*)alloc((size_t)LAYERS * 512 * 128 * 2);
    __hip_bfloat16* Wti = (__hip_bfloat16*)alloc((size_t)HID * IN_DIM * 2);
    __hip_bfloat16* xb  = (__hip_bfloat16*)alloc((size_t)N_NODES * IN_DIM * 2);
    float* a_s    = (float*)alloc((size_t)N_NODES * HEADS * 4);
    float* a_d    = (float*)alloc((size_t)N_NODES * HEADS * 4);
    int* row_ptr  = (int*)alloc((N_NODES + 1) * 4);
    int* cursor   = (int*)alloc(N_NODES * 4);
    int* colidx   = (int*)alloc((size_t)TOT_E * 4);
    int* counts   = (int*)alloc(N_NODES * 4);

    zero_kernel<<<(N_NODES + 255) / 256, 256, 0, stream>>>(counts);
    count_kernel<<<(TOT_E + 255) / 256, 256, 0, stream>>>(ei, counts);
    scan_kernel<<<1, 1024, 0, stream>>>(counts, row_ptr, cursor);
    fill_kernel<<<(TOT_E + 255) / 256, 256, 0, stream>>>(ei, cursor, colidx);
    pack_all<<<(NW + NWIN + NX + 255) / 256, 256, 0, stream>>>(Ws, W_in, x, Wt, Wti, xb);

    gemm_in<<<(N_NODES + 63) / 64, 256, 0, stream>>>(xb, Wti, b_in, h, hb);

    for (int l = 0; l < LAYERS; ++l) {
        gemm_mfma<<<(N_NODES + 63) / 64, 256, 0, stream>>>(
            hb, Wt + (size_t)l * 512 * 128,
            att_src + (size_t)l * HEADS * HID, att_dst + (size_t)l * HEADS * HID,
            hpj, a_s, a_d);
        edge_kernel<<<(N_NODES + 3) / 4, 256, 0, stream>>>(
            row_ptr, colidx, hpj, a_s, a_d,
            conv_b + (size_t)l * HID, ln_g + (size_t)l * HID, ln_b + (size_t)l * HID,
            h, hb);
    }

    pool2_kernel<<<GRAPHS, 128, 0, stream>>>(h, batch, out);
}